// Round 9
// baseline (135.393 us; speedup 1.0000x reference)
//
#include <hip/hip_runtime.h>
#include <math.h>

#define NS 4
#define NC 128
#define HH 64
#define WW 64
#define LL 1024   // 32*32

typedef unsigned short u16;
typedef u16 u16x4 __attribute__((ext_vector_type(4)));
typedef short s16x8 __attribute__((ext_vector_type(8)));
typedef float f32x4 __attribute__((ext_vector_type(4)));

__device__ __forceinline__ u16 f2bf(float x) {
  unsigned u = __float_as_uint(x);
  return (u16)((u + 0x7FFFu + ((u >> 16) & 1u)) >> 16);
}
__device__ __forceinline__ float bf2f(u16 h) {
  return __uint_as_float(((unsigned)h) << 16);
}

// ---------------- prep v2: coalesced LDS-transpose. One block per (s, qh).
// Outputs bsT/fsT hi/lo [s][q][c] and Q[s][q] = patch ssq.
__global__ __launch_bounds__(256) void prep(const float* __restrict__ f,
                                            const float* __restrict__ b,
                                            u16* __restrict__ bsT_hi, u16* __restrict__ bsT_lo,
                                            u16* __restrict__ fsT_hi, u16* __restrict__ fsT_lo,
                                            float* __restrict__ Q) {
  int bx = blockIdx.x;             // 128 = 4s * 32qh
  int qh = bx & 31, s = bx >> 5;
  int t = threadIdx.x;
  __shared__ float Lb[32][132];    // [even-w][c], 16B-aligned rows
  __shared__ float Lf[32][132];
  __shared__ float SS[256];
  const float* brow = b + ((size_t)(s * NC) * HH + 2 * qh) * WW;
  const float* frow = f + ((size_t)(s * NC) * HH + 2 * qh) * WW;
#pragma unroll
  for (int i = 0; i < 8; ++i) {
    int task = i * 256 + t;        // c = task>>4, j = task&15 (w-quad)
    int c = task >> 4, j = task & 15;
    float4 vb = *(const float4*)(brow + (size_t)c * (HH * WW) + 4 * j);
    float4 vf = *(const float4*)(frow + (size_t)c * (HH * WW) + 4 * j);
    Lb[2 * j][c] = vb.x; Lb[2 * j + 1][c] = vb.z;
    Lf[2 * j][c] = vf.x; Lf[2 * j + 1][c] = vf.z;
  }
  __syncthreads();
  int qw = t >> 3, co = (t & 7) * 16;
  int q = qh * 32 + qw;
  float ssq = 0.f;
  s16x8 vbh0, vbh1, vbl0, vbl1, vfh0, vfh1, vfl0, vfl1;
#pragma unroll
  for (int e = 0; e < 8; ++e) {
    float xb = Lb[qw][co + e], xf = Lf[qw][co + e];
    ssq += xb * xb;
    u16 hb = f2bf(xb); u16 lb = f2bf(xb - bf2f(hb));
    u16 hf = f2bf(xf); u16 lf = f2bf(xf - bf2f(hf));
    vbh0[e] = (short)hb; vbl0[e] = (short)lb; vfh0[e] = (short)hf; vfl0[e] = (short)lf;
  }
#pragma unroll
  for (int e = 0; e < 8; ++e) {
    float xb = Lb[qw][co + 8 + e], xf = Lf[qw][co + 8 + e];
    ssq += xb * xb;
    u16 hb = f2bf(xb); u16 lb = f2bf(xb - bf2f(hb));
    u16 hf = f2bf(xf); u16 lf = f2bf(xf - bf2f(hf));
    vbh1[e] = (short)hb; vbl1[e] = (short)lb; vfh1[e] = (short)hf; vfl1[e] = (short)lf;
  }
  size_t o = ((size_t)(s * LL) + q) * NC + co;
  *(s16x8*)(bsT_hi + o) = vbh0; *(s16x8*)(bsT_hi + o + 8) = vbh1;
  *(s16x8*)(bsT_lo + o) = vbl0; *(s16x8*)(bsT_lo + o + 8) = vbl1;
  *(s16x8*)(fsT_hi + o) = vfh0; *(s16x8*)(fsT_hi + o + 8) = vfh1;
  *(s16x8*)(fsT_lo + o) = vfl0; *(s16x8*)(fsT_lo + o + 8) = vfl1;
  SS[t] = ssq;
  __syncthreads();
  if (t < 32) {
    float sum = 0.f;
#pragma unroll
    for (int j = 0; j < 8; ++j) sum += SS[t * 8 + j];
    Q[s * LL + qh * 32 + t] = sum;
  }
}

// ---------------- prep_wt v2: coalesced. Thread = (s,c,kh,kw-octet); reads both
// parities densely, emits all 4 cls as u16x8.
__global__ __launch_bounds__(256) void prep_wt(const float* __restrict__ b,
                                               u16* __restrict__ Wt) {
  int idx = blockIdx.x * 256 + threadIdx.x;      // 65536 = 4s*128c*32kh*4ko
  int ko = idx & 3, kh = (idx >> 2) & 31, c = (idx >> 7) & 127, s = idx >> 14;
  const float* base0 = b + ((size_t)(s * NC + c) * HH + 2 * kh) * WW + 16 * ko;
  const float* base1 = base0 + WW;
  float4 a0 = ((const float4*)base0)[0];
  float4 a1 = ((const float4*)base0)[1];
  float4 a2 = ((const float4*)base0)[2];
  float4 a3 = ((const float4*)base0)[3];
  float4 c0 = ((const float4*)base1)[0];
  float4 c1 = ((const float4*)base1)[1];
  float4 c2 = ((const float4*)base1)[2];
  float4 c3 = ((const float4*)base1)[3];
  s16x8 w0, w1, w2, w3;
  w0[0]=(short)f2bf(a0.x); w0[1]=(short)f2bf(a0.z); w0[2]=(short)f2bf(a1.x); w0[3]=(short)f2bf(a1.z);
  w0[4]=(short)f2bf(a2.x); w0[5]=(short)f2bf(a2.z); w0[6]=(short)f2bf(a3.x); w0[7]=(short)f2bf(a3.z);
  w1[0]=(short)f2bf(a0.y); w1[1]=(short)f2bf(a0.w); w1[2]=(short)f2bf(a1.y); w1[3]=(short)f2bf(a1.w);
  w1[4]=(short)f2bf(a2.y); w1[5]=(short)f2bf(a2.w); w1[6]=(short)f2bf(a3.y); w1[7]=(short)f2bf(a3.w);
  w2[0]=(short)f2bf(c0.x); w2[1]=(short)f2bf(c0.z); w2[2]=(short)f2bf(c1.x); w2[3]=(short)f2bf(c1.z);
  w2[4]=(short)f2bf(c2.x); w2[5]=(short)f2bf(c2.z); w2[6]=(short)f2bf(c3.x); w2[7]=(short)f2bf(c3.z);
  w3[0]=(short)f2bf(c0.y); w3[1]=(short)f2bf(c0.w); w3[2]=(short)f2bf(c1.y); w3[3]=(short)f2bf(c1.w);
  w3[4]=(short)f2bf(c2.y); w3[5]=(short)f2bf(c2.w); w3[6]=(short)f2bf(c3.y); w3[7]=(short)f2bf(c3.w);
  int koff = kh * 32 + 8 * ko;
  *(s16x8*)(Wt + (((size_t)((s * 4 + 0) * NC + c)) << 10) + koff) = w0;
  *(s16x8*)(Wt + (((size_t)((s * 4 + 1) * NC + c)) << 10) + koff) = w1;
  *(s16x8*)(Wt + (((size_t)((s * 4 + 2) * NC + c)) << 10) + koff) = w2;
  *(s16x8*)(Wt + (((size_t)((s * 4 + 3) * NC + c)) << 10) + koff) = w3;
}

// ---------------- aux: nrm[p] (9-tap of Q + eps) and mmv[p]
__global__ __launch_bounds__(1024) void aux_nrm(const float* __restrict__ Q,
                                                const float* __restrict__ mask,
                                                float* __restrict__ nrm,
                                                float* __restrict__ mmv) {
  int s = blockIdx.x;
  int p = threadIdx.x;
  __shared__ float Ql[LL];
  __shared__ float M[LL];
  Ql[p] = Q[s * LL + p];
  int ph = p >> 5, pw = p & 31;
  M[p] = mask[s * HH * WW + (2 * ph) * WW + 2 * pw];
  __syncthreads();
  float sum2 = 1152 * 1e-4f;
  float msum = 0.f;
#pragma unroll
  for (int dh = -1; dh <= 1; ++dh)
#pragma unroll
    for (int dw = -1; dw <= 1; ++dw) {
      int h = ph + dh, w = pw + dw;
      if (h >= 0 && h < 32 && w >= 0 && w < 32) {
        sum2 += Ql[h * 32 + w];
        msum += M[h * 32 + w];
      }
    }
  nrm[s * LL + p] = sqrtf(sum2);
  mmv[s * LL + p] = msum * (1.f / 9.f);
}

// ---------------- Gt[q][p] = sum_c fs[c][q]*bs[c][p], split-bf16 MFMA,
// 4 waves/block, 4 n-tiles/wave, 2-deep prefetch over K=128
__global__ __launch_bounds__(256) void gram_mfma(const u16* __restrict__ aT_hi,
                                                 const u16* __restrict__ aT_lo,
                                                 const u16* __restrict__ bT_hi,
                                                 const u16* __restrict__ bT_lo,
                                                 float* __restrict__ G) {
  int wid = blockIdx.x * 4 + (threadIdx.x >> 6);  // 4096 = 4s * 64mt * 16ngg
  int ngg = wid & 15, mt = (wid >> 4) & 63, s = wid >> 10;
  int l = threadIdx.x & 63, lr = l & 15, lg = l >> 4;
  const u16* Ah = aT_hi + ((size_t)(s * LL) + mt * 16 + lr) * NC + lg * 8;
  const u16* Al = aT_lo + ((size_t)(s * LL) + mt * 16 + lr) * NC + lg * 8;
  size_t bbase = ((size_t)(s * LL) + ngg * 64 + lr) * NC + lg * 8;
  f32x4 acc[4] = {};
  s16x8 ah0, al0, bh0[4], bl0[4];
  s16x8 ah1, al1, bh1[4], bl1[4];
  auto LD = [&](int kc, s16x8& ah, s16x8& al, s16x8* bh, s16x8* bl) {
    int o = kc * 32;
    ah = *(const s16x8*)(Ah + o);
    al = *(const s16x8*)(Al + o);
#pragma unroll
    for (int nt = 0; nt < 4; ++nt) {
      bh[nt] = *(const s16x8*)(bT_hi + bbase + nt * 16 * NC + o);
      bl[nt] = *(const s16x8*)(bT_lo + bbase + nt * 16 * NC + o);
    }
  };
  auto ST = [&](s16x8& ah, s16x8& al, s16x8* bh, s16x8* bl) {
#pragma unroll
    for (int nt = 0; nt < 4; ++nt) {
      acc[nt] = __builtin_amdgcn_mfma_f32_16x16x32_bf16(ah, bh[nt], acc[nt], 0, 0, 0);
      acc[nt] = __builtin_amdgcn_mfma_f32_16x16x32_bf16(ah, bl[nt], acc[nt], 0, 0, 0);
      acc[nt] = __builtin_amdgcn_mfma_f32_16x16x32_bf16(al, bh[nt], acc[nt], 0, 0, 0);
    }
  };
  LD(0, ah0, al0, bh0, bl0);
  LD(1, ah1, al1, bh1, bl1);
  ST(ah0, al0, bh0, bl0);
  LD(2, ah0, al0, bh0, bl0);
  ST(ah1, al1, bh1, bl1);
  LD(3, ah1, al1, bh1, bl1);
  ST(ah0, al0, bh0, bl0);
  ST(ah1, al1, bh1, bl1);
  float* Gs = G + ((size_t)s << 20);
  int qrow = mt * 16 + lg * 4;
#pragma unroll
  for (int nt = 0; nt < 4; ++nt) {
    int p0 = ngg * 64 + nt * 16 + lr;
#pragma unroll
    for (int r = 0; r < 4; ++r)
      Gs[(size_t)(qrow + r) * LL + p0] = acc[nt][r];
  }
}

// ---------------- sbuildT v3: 4 q per block (same qh), 18-row shared stage.
__global__ __launch_bounds__(256) void sbuildT(const float* __restrict__ Gt,
                                               const float* __restrict__ nrm,
                                               float* __restrict__ St) {
  int g = blockIdx.x;              // 1024 = 4s * 32qh * 8qg
  int qg = g & 7, qh = (g >> 3) & 31, s = g >> 8;
  int qw0 = qg * 4;
  int t = threadIdx.x;
  __shared__ float L[18][1024];    // 72 KB
  const float* Gs = Gt + ((size_t)s << 20);
#pragma unroll
  for (int slot = 0; slot < 18; ++slot) {
    int dh = slot / 6 - 1, j = slot % 6;
    int qh2 = qh + dh, qw2 = qw0 - 1 + j;
    bool ok = ((unsigned)qh2 < 32u) && ((unsigned)qw2 < 32u);
    float4 val = ok ? *(const float4*)(Gs + ((size_t)(qh2 * 32 + qw2) << 10) + t * 4)
                    : make_float4(0.f, 0.f, 0.f, 0.f);
    *(float4*)&L[slot][t * 4] = val;
  }
  __syncthreads();
  const float* nr = nrm + s * LL;
#pragma unroll
  for (int ii = 0; ii < 4; ++ii) {
    int p = ii * 256 + t;
    int ph = p >> 5, pw = p & 31;
    float nrp = nr[p];
#pragma unroll
    for (int qq = 0; qq < 4; ++qq) {
      float acc = 0.f;
#pragma unroll
      for (int dh = -1; dh <= 1; ++dh)
#pragma unroll
        for (int dw = -1; dw <= 1; ++dw) {
          int ph2 = ph + dh, pw2 = pw + dw;
          if ((unsigned)ph2 < 32u && (unsigned)pw2 < 32u)
            acc += L[(dh + 1) * 6 + qq + dw + 1][p + dh * 32 + dw];
        }
      St[((size_t)s << 20) + ((size_t)(qh * 32 + qw0 + qq) << 10) + p] = acc / nrp;
    }
  }
}

// ---------------- fuse12_softmax v3: 4 q per block, 18-row shared stage,
// per-row softmax over p with block reduction.
__global__ __launch_bounds__(256) void fuse12_softmax(const float* __restrict__ St,
                                                      const float* __restrict__ mmv,
                                                      float* __restrict__ yiT) {
  int g = blockIdx.x;              // 1024 = 4s * 32qh * 8qg
  int qg = g & 7, qh = (g >> 3) & 31, s = g >> 8;
  int qw0 = qg * 4;
  int q0 = qh * 32 + qw0;
  int t = threadIdx.x;
  int lane = t & 63, wv = t >> 6;
  __shared__ float L[18][1024];    // 72 KB
  __shared__ float redA[4][4];
  __shared__ float redB[4][4];
  const float* Ss = St + ((size_t)s << 20);
  const float* mm = mmv + s * LL;
  int base[3];
  base[0] = (qh > 0) ? (q0 - 33) : (992 + qw0 - 2);
  base[1] = q0 - 1;
  base[2] = (qh < 31) ? (q0 + 31) : qw0;
#pragma unroll
  for (int slot = 0; slot < 18; ++slot) {
    int d2 = slot / 6, j = slot % 6;
    int row = base[d2] + j;
    bool ok = (unsigned)row < 1024u;
    float4 val = ok ? *(const float4*)(Ss + ((size_t)row << 10) + t * 4)
                    : make_float4(0.f, 0.f, 0.f, 0.f);
    *(float4*)&L[slot][t * 4] = val;
  }
  __syncthreads();
  // per-q validity of the remap groups
  bool vq0[4], vq2[4];
#pragma unroll
  for (int qq = 0; qq < 4; ++qq) {
    int qw = qw0 + qq;
    vq0[qq] = !(qh == 0 && qw == 0);
    vq2[qq] = !(qh == 31 && qw == 31);
  }
  float v[4][4];                   // [ii][qq]
  float mval[4];
  float mxq[4] = {-1e30f, -1e30f, -1e30f, -1e30f};
#pragma unroll
  for (int ii = 0; ii < 4; ++ii) {
    int p = ii * 256 + t;
    int ph = p >> 5, pw = p & 31;
    int rp[3]; bool vp[3];
    if (ph > 0)      { rp[0] = p - 32;        vp[0] = true; }
    else if (pw > 0) { rp[0] = 992 + pw - 1;  vp[0] = true; }
    else             { rp[0] = 0;             vp[0] = false; }
    rp[1] = p; vp[1] = true;
    if (ph < 31)      { rp[2] = p + 32;   vp[2] = true; }
    else if (pw < 31) { rp[2] = pw + 1;   vp[2] = true; }
    else              { rp[2] = 0;        vp[2] = false; }
    mval[ii] = mm[p];
#pragma unroll
    for (int qq = 0; qq < 4; ++qq) {
      float acc = 0.f;
#pragma unroll
      for (int d2 = 0; d2 < 3; ++d2) {
        bool vq = (d2 == 0) ? vq0[qq] : ((d2 == 2) ? vq2[qq] : true);
        if (vq && vp[d2]) {
#pragma unroll
          for (int d1 = -1; d1 <= 1; ++d1) {
            int cc = rp[d2] + d1;
            if ((unsigned)cc < 1024u)
              acc += L[d2 * 6 + qq + d1 + 1][cc];
          }
        }
      }
      float val = acc * mval[ii] * 10.f;
      v[ii][qq] = val;
      mxq[qq] = fmaxf(mxq[qq], val);
    }
  }
#pragma unroll
  for (int qq = 0; qq < 4; ++qq) {
    float m = mxq[qq];
#pragma unroll
    for (int o = 32; o; o >>= 1) m = fmaxf(m, __shfl_xor(m, o));
    if (lane == 0) redA[wv][qq] = m;
  }
  __syncthreads();
  float fm[4], sq[4] = {0.f, 0.f, 0.f, 0.f};
#pragma unroll
  for (int qq = 0; qq < 4; ++qq)
    fm[qq] = fmaxf(fmaxf(redA[0][qq], redA[1][qq]), fmaxf(redA[2][qq], redA[3][qq]));
#pragma unroll
  for (int ii = 0; ii < 4; ++ii)
#pragma unroll
    for (int qq = 0; qq < 4; ++qq) {
      v[ii][qq] = __expf(v[ii][qq] - fm[qq]);
      sq[qq] += v[ii][qq];
    }
#pragma unroll
  for (int qq = 0; qq < 4; ++qq) {
    float sm = sq[qq];
#pragma unroll
    for (int o = 32; o; o >>= 1) sm += __shfl_xor(sm, o);
    if (lane == 0) redB[wv][qq] = sm;
  }
  __syncthreads();
  float inv[4];
#pragma unroll
  for (int qq = 0; qq < 4; ++qq)
    inv[qq] = 1.f / ((redB[0][qq] + redB[1][qq]) + (redB[2][qq] + redB[3][qq]));
#pragma unroll
  for (int qq = 0; qq < 4; ++qq) {
    float* yo = yiT + ((size_t)s << 20) + ((size_t)(q0 + qq) << 10);
#pragma unroll
    for (int ii = 0; ii < 4; ++ii) {
      int p = ii * 256 + t;
      yo[p] = v[ii][qq] * inv[qq] * mval[ii];
    }
  }
}

// ---------------- build P (4-tap diagonal sums of yiT) as bf16; one block per
// (s, ih, 4-jw strip): 18-row LDS stage shared by 4 n x 4 cls outputs
__global__ __launch_bounds__(256) void build_p(const float* __restrict__ yiT,
                                               u16* __restrict__ Pb) {
  int bx = blockIdx.x;               // 1024 = 4s * 32ih * 8jg
  int jg = bx & 7, ih = (bx >> 3) & 31, s = bx >> 8;
  int jw0 = jg * 4;
  const float* Y = yiT + ((size_t)s << 20);
  __shared__ float R[18][1024];      // [di*6+jj][k]
  int t = threadIdx.x;
#pragma unroll
  for (int r = 0; r < 18; ++r) {
    int di = r / 6, jj = r % 6;
    int ihh = ih + di - 1, jww = jw0 + jj - 1;
    bool vld = ((unsigned)ihh < 32u) && ((unsigned)jww < 32u);
    float4 val = vld ? *(const float4*)(Y + ((size_t)(ihh * 32 + jww) << 10) + t * 4)
                     : make_float4(0.f, 0.f, 0.f, 0.f);
    *(float4*)&R[r][t * 4] = val;
  }
  __syncthreads();
  int nl = t >> 6, lane = t & 63;
  int n = ih * 32 + jw0 + nl;
#pragma unroll
  for (int kq = 0; kq < 4; ++kq) {
    int k0 = (kq * 64 + lane) * 4;
    int kh = k0 >> 5;
#pragma unroll
    for (int cls = 0; cls < 4; ++cls) {
      int py = cls >> 1, px = cls & 1;
      int sy = py ? 1 : -1, sx = px ? 1 : -1;
      const float* RA = R[6 + nl + 1];
      const float* RB = R[(1 + sy) * 6 + nl + 1];
      const float* RC = R[6 + nl + 1 + sx];
      const float* RD = R[(1 + sy) * 6 + nl + 1 + sx];
      bool mB = (unsigned)(kh + sy) < 32u;
      int ob = 32 * sy;
      u16x4 pk;
#pragma unroll
      for (int e = 0; e < 4; ++e) {
        int k = k0 + e, kw = k & 31;
        bool mC = (unsigned)(kw + sx) < 32u;
        float v = RA[k];
        if (mB) v += RB[k + ob];
        if (mC) v += RC[k + sx];
        if (mB && mC) v += RD[k + ob + sx];
        pk[e] = f2bf(v);
      }
      int zz = s * 4 + cls;
      *(u16x4*)(Pb + (((size_t)(zz * LL + n)) << 10) + k0) = pk;
    }
  }
}

// ---------------- deconv GEMM v3: wave = 32c x 64n, block = 4 waves (64c x 128n),
// grid 256 = 16z * 2cb * 8nb, depth-4 register prefetch, K=1024
#define DGLD(i, kc) { int o = (kc) * 32;                      \
    A##i##0 = *(const s16x8*)(Ap0 + o);                       \
    A##i##1 = *(const s16x8*)(Ap1 + o);                       \
    B##i##0 = *(const s16x8*)(Bp0 + o);                       \
    B##i##1 = *(const s16x8*)(Bp1 + o);                       \
    B##i##2 = *(const s16x8*)(Bp2 + o);                       \
    B##i##3 = *(const s16x8*)(Bp3 + o); }
#define DGST(i) {                                                                     \
    acc[0][0] = __builtin_amdgcn_mfma_f32_16x16x32_bf16(A##i##0, B##i##0, acc[0][0], 0, 0, 0); \
    acc[0][1] = __builtin_amdgcn_mfma_f32_16x16x32_bf16(A##i##0, B##i##1, acc[0][1], 0, 0, 0); \
    acc[0][2] = __builtin_amdgcn_mfma_f32_16x16x32_bf16(A##i##0, B##i##2, acc[0][2], 0, 0, 0); \
    acc[0][3] = __builtin_amdgcn_mfma_f32_16x16x32_bf16(A##i##0, B##i##3, acc[0][3], 0, 0, 0); \
    acc[1][0] = __builtin_amdgcn_mfma_f32_16x16x32_bf16(A##i##1, B##i##0, acc[1][0], 0, 0, 0); \
    acc[1][1] = __builtin_amdgcn_mfma_f32_16x16x32_bf16(A##i##1, B##i##1, acc[1][1], 0, 0, 0); \
    acc[1][2] = __builtin_amdgcn_mfma_f32_16x16x32_bf16(A##i##1, B##i##2, acc[1][2], 0, 0, 0); \
    acc[1][3] = __builtin_amdgcn_mfma_f32_16x16x32_bf16(A##i##1, B##i##3, acc[1][3], 0, 0, 0); }

__global__ __launch_bounds__(256, 1) void deconv_gemm(const u16* __restrict__ Pb,
                                                      const u16* __restrict__ Wt,
                                                      float* __restrict__ out) {
  int bx = blockIdx.x;               // 256 = 16z * 2cb * 8nb
  int nb = bx & 7, cb = (bx >> 3) & 1, z = bx >> 4;
  int s = z >> 2, cls = z & 3, py = cls >> 1, px = cls & 1;
  int wz = threadIdx.x >> 6;
  int wc = wz >> 1, wn = wz & 1;
  int l = threadIdx.x & 63, lr = l & 15, lg = l >> 4;
  int c0 = cb * 64 + wc * 32;
  int n0 = nb * 128 + wn * 64;
  const u16* Ap0 = Wt + ((size_t)z * NC + c0 + lr) * LL + lg * 8;
  const u16* Ap1 = Ap0 + (size_t)16 * LL;
  const u16* Bp0 = Pb + ((size_t)(z * LL + n0 + lr)) * LL + lg * 8;
  const u16* Bp1 = Bp0 + (size_t)16 * LL;
  const u16* Bp2 = Bp0 + (size_t)32 * LL;
  const u16* Bp3 = Bp0 + (size_t)48 * LL;
  f32x4 acc[2][4] = {};
  s16x8 A00, A01, B00, B01, B02, B03;
  s16x8 A10, A11, B10, B11, B12, B13;
  s16x8 A20, A21, B20, B21, B22, B23;
  s16x8 A30, A31, B30, B31, B32, B33;
  DGLD(0, 0) DGLD(1, 1) DGLD(2, 2) DGLD(3, 3)
#pragma unroll
  for (int kc = 0; kc < 32; kc += 4) {
    DGST(0) if (kc + 4 < 32) DGLD(0, kc + 4)
    DGST(1) if (kc + 5 < 32) DGLD(1, kc + 5)
    DGST(2) if (kc + 6 < 32) DGLD(2, kc + 6)
    DGST(3) if (kc + 7 < 32) DGLD(3, kc + 7)
  }
  float* os = out + (size_t)s * NC * HH * WW;
#pragma unroll
  for (int mt = 0; mt < 2; ++mt) {
    int cc = c0 + mt * 16 + lg * 4;
#pragma unroll
    for (int nt = 0; nt < 4; ++nt) {
      int nn = n0 + nt * 16 + lr;
      size_t ob = (size_t)(2 * (nn >> 5) + py) * WW + 2 * (nn & 31) + px;
#pragma unroll
      for (int r = 0; r < 4; ++r)
        os[(size_t)(cc + r) * (HH * WW) + ob] = acc[mt][nt][r] * 0.25f;
    }
  }
}

extern "C" void kernel_launch(void* const* d_in, const int* in_sizes, int n_in,
                              void* d_out, int out_size, void* d_ws, size_t ws_size,
                              hipStream_t stream) {
  const float* f    = (const float*)d_in[0];
  const float* b    = (const float*)d_in[1];
  const float* mask = (const float*)d_in[2];
  float* out  = (float*)d_out;

  // workspace layout: ~74 MB
  float* buf0 = (float*)d_ws;              // 4,194,304 f (Gt -> yiT)
  float* buf1 = buf0 + 4194304;            // 4,194,304 f (St)
  u16* bsT_hi = (u16*)(buf1 + 4194304);    // 524,288 u16 each
  u16* bsT_lo = bsT_hi + 524288;
  u16* fsT_hi = bsT_lo + 524288;
  u16* fsT_lo = fsT_hi + 524288;
  u16* Wt     = fsT_lo + 524288;           // 2,097,152 u16
  float* Q    = (float*)(Wt + 2097152);    // 4,096
  float* nrm  = Q + 4096;                  // 4,096
  float* mmv  = nrm + 4096;                // 4,096
  u16* Pb     = (u16*)(mmv + 4096);        // 16,777,216 u16 (32 MB, all 16 z)

  hipLaunchKernelGGL(prep, dim3(128), dim3(256), 0, stream, f, b, bsT_hi, bsT_lo, fsT_hi, fsT_lo, Q);
  hipLaunchKernelGGL(prep_wt, dim3(256), dim3(256), 0, stream, b, Wt);
  hipLaunchKernelGGL(aux_nrm, dim3(4), dim3(1024), 0, stream, Q, mask, nrm, mmv);
  hipLaunchKernelGGL(gram_mfma, dim3(1024), dim3(256), 0, stream, fsT_hi, fsT_lo, bsT_hi, bsT_lo, buf0);
  hipLaunchKernelGGL(sbuildT, dim3(1024), dim3(256), 0, stream, buf0, nrm, buf1);
  hipLaunchKernelGGL(fuse12_softmax, dim3(1024), dim3(256), 0, stream, buf1, mmv, buf0);
  hipLaunchKernelGGL(build_p, dim3(1024), dim3(256), 0, stream, buf0, Pb);
  hipLaunchKernelGGL(deconv_gemm, dim3(256), dim3(256), 0, stream, Pb, Wt, out);
}

// Round 10
// 134.726 us; speedup vs baseline: 1.0050x; 1.0050x over previous
//
#include <hip/hip_runtime.h>
#include <math.h>

#define NS 4
#define NC 128
#define HH 64
#define WW 64
#define LL 1024   // 32*32

typedef unsigned short u16;
typedef u16 u16x4 __attribute__((ext_vector_type(4)));
typedef short s16x8 __attribute__((ext_vector_type(8)));
typedef float f32x4 __attribute__((ext_vector_type(4)));

__device__ __forceinline__ u16 f2bf(float x) {
  unsigned u = __float_as_uint(x);
  return (u16)((u + 0x7FFFu + ((u >> 16) & 1u)) >> 16);
}
__device__ __forceinline__ float bf2f(u16 h) {
  return __uint_as_float(((unsigned)h) << 16);
}

// ---------------- prep v3: coalesced LDS-transpose, c split across 2 blocks.
// One block per (s, qh, cg). Outputs bsT/fsT hi/lo [s][q][c], Qp[cg][s][q] partial ssq.
__global__ __launch_bounds__(256) void prep(const float* __restrict__ f,
                                            const float* __restrict__ b,
                                            u16* __restrict__ bsT_hi, u16* __restrict__ bsT_lo,
                                            u16* __restrict__ fsT_hi, u16* __restrict__ fsT_lo,
                                            float* __restrict__ Qp) {
  int bx = blockIdx.x;             // 256 = 4s * 32qh * 2cg
  int cg = bx & 1, qh = (bx >> 1) & 31, s = bx >> 6;
  int t = threadIdx.x;
  __shared__ float Lb[32][68];     // [even-w][c-local]
  __shared__ float Lf[32][68];
  __shared__ float SS[256];
  const float* brow = b + ((size_t)(s * NC + cg * 64) * HH + 2 * qh) * WW;
  const float* frow = f + ((size_t)(s * NC + cg * 64) * HH + 2 * qh) * WW;
#pragma unroll
  for (int i = 0; i < 4; ++i) {
    int task = i * 256 + t;        // 1024 = 64c * 16 w-quads
    int c = task >> 4, j = task & 15;
    float4 vb = *(const float4*)(brow + (size_t)c * (HH * WW) + 4 * j);
    float4 vf = *(const float4*)(frow + (size_t)c * (HH * WW) + 4 * j);
    Lb[2 * j][c] = vb.x; Lb[2 * j + 1][c] = vb.z;
    Lf[2 * j][c] = vf.x; Lf[2 * j + 1][c] = vf.z;
  }
  __syncthreads();
  int qw = t >> 3, og = t & 7;
  int col = og * 8;
  int q = qh * 32 + qw;
  float ssq = 0.f;
  s16x8 vbh, vbl, vfh, vfl;
#pragma unroll
  for (int e = 0; e < 8; ++e) {
    float xb = Lb[qw][col + e], xf = Lf[qw][col + e];
    ssq += xb * xb;
    u16 hb = f2bf(xb); u16 lb = f2bf(xb - bf2f(hb));
    u16 hf = f2bf(xf); u16 lf = f2bf(xf - bf2f(hf));
    vbh[e] = (short)hb; vbl[e] = (short)lb; vfh[e] = (short)hf; vfl[e] = (short)lf;
  }
  size_t o = ((size_t)(s * LL) + q) * NC + cg * 64 + col;
  *(s16x8*)(bsT_hi + o) = vbh;
  *(s16x8*)(bsT_lo + o) = vbl;
  *(s16x8*)(fsT_hi + o) = vfh;
  *(s16x8*)(fsT_lo + o) = vfl;
  SS[t] = ssq;
  __syncthreads();
  if (og == 0) {
    float sum = 0.f;
#pragma unroll
    for (int j = 0; j < 8; ++j) sum += SS[qw * 8 + j];
    Qp[cg * (NS * LL) + s * LL + q] = sum;
  }
}

// ---------------- prep_wt v3: LDS-staged, coalesced in and out.
// One block per (s, c, khg): stage 16 rows (8 kh x 2 parity), emit 4 cls.
__global__ __launch_bounds__(256) void prep_wt(const float* __restrict__ b,
                                               u16* __restrict__ Wt) {
  int bx = blockIdx.x;             // 2048 = 4s * 128c * 4khg
  int khg = bx & 3, c = (bx >> 2) & 127, s = bx >> 9;
  int t = threadIdx.x;
  __shared__ float Lw[16][65];
  const float* src = b + ((size_t)(s * NC + c) * HH + 16 * khg) * WW;
  float4 v = *(const float4*)(src + (t >> 4) * WW + (t & 15) * 4);
  int rr = t >> 4, qq4 = (t & 15) * 4;
  Lw[rr][qq4] = v.x; Lw[rr][qq4 + 1] = v.y; Lw[rr][qq4 + 2] = v.z; Lw[rr][qq4 + 3] = v.w;
  __syncthreads();
  if (t < 128) {
    int cls = t >> 5, kh_l = (t >> 2) & 7, ko = t & 3;
    int py = cls >> 1, px = cls & 1;
    int y = 2 * kh_l + py;
    s16x8 w;
#pragma unroll
    for (int e = 0; e < 8; ++e) w[e] = (short)f2bf(Lw[y][16 * ko + 2 * e + px]);
    int kh = khg * 8 + kh_l;
    int z = s * 4 + cls;
    *(s16x8*)(Wt + (((size_t)(z * NC + c)) << 10) + kh * 32 + 8 * ko) = w;
  }
}

// ---------------- aux: nrm[p] (9-tap of Q + eps) and mmv[p]
__global__ __launch_bounds__(1024) void aux_nrm(const float* __restrict__ Qp,
                                                const float* __restrict__ mask,
                                                float* __restrict__ nrm,
                                                float* __restrict__ mmv) {
  int s = blockIdx.x;
  int p = threadIdx.x;
  __shared__ float Ql[LL];
  __shared__ float M[LL];
  Ql[p] = Qp[s * LL + p] + Qp[NS * LL + s * LL + p];
  int ph = p >> 5, pw = p & 31;
  M[p] = mask[s * HH * WW + (2 * ph) * WW + 2 * pw];
  __syncthreads();
  float sum2 = 1152 * 1e-4f;
  float msum = 0.f;
#pragma unroll
  for (int dh = -1; dh <= 1; ++dh)
#pragma unroll
    for (int dw = -1; dw <= 1; ++dw) {
      int h = ph + dh, w = pw + dw;
      if (h >= 0 && h < 32 && w >= 0 && w < 32) {
        sum2 += Ql[h * 32 + w];
        msum += M[h * 32 + w];
      }
    }
  nrm[s * LL + p] = sqrtf(sum2);
  mmv[s * LL + p] = msum * (1.f / 9.f);
}

// ---------------- Gt[q][p] = sum_c fs[c][q]*bs[c][p], split-bf16 MFMA,
// 4 waves/block, 4 n-tiles/wave, 2-deep prefetch over K=128
__global__ __launch_bounds__(256) void gram_mfma(const u16* __restrict__ aT_hi,
                                                 const u16* __restrict__ aT_lo,
                                                 const u16* __restrict__ bT_hi,
                                                 const u16* __restrict__ bT_lo,
                                                 float* __restrict__ G) {
  int wid = blockIdx.x * 4 + (threadIdx.x >> 6);  // 4096 = 4s * 64mt * 16ngg
  int ngg = wid & 15, mt = (wid >> 4) & 63, s = wid >> 10;
  int l = threadIdx.x & 63, lr = l & 15, lg = l >> 4;
  const u16* Ah = aT_hi + ((size_t)(s * LL) + mt * 16 + lr) * NC + lg * 8;
  const u16* Al = aT_lo + ((size_t)(s * LL) + mt * 16 + lr) * NC + lg * 8;
  size_t bbase = ((size_t)(s * LL) + ngg * 64 + lr) * NC + lg * 8;
  f32x4 acc[4] = {};
  s16x8 ah0, al0, bh0[4], bl0[4];
  s16x8 ah1, al1, bh1[4], bl1[4];
  auto LD = [&](int kc, s16x8& ah, s16x8& al, s16x8* bh, s16x8* bl) {
    int o = kc * 32;
    ah = *(const s16x8*)(Ah + o);
    al = *(const s16x8*)(Al + o);
#pragma unroll
    for (int nt = 0; nt < 4; ++nt) {
      bh[nt] = *(const s16x8*)(bT_hi + bbase + nt * 16 * NC + o);
      bl[nt] = *(const s16x8*)(bT_lo + bbase + nt * 16 * NC + o);
    }
  };
  auto ST = [&](s16x8& ah, s16x8& al, s16x8* bh, s16x8* bl) {
#pragma unroll
    for (int nt = 0; nt < 4; ++nt) {
      acc[nt] = __builtin_amdgcn_mfma_f32_16x16x32_bf16(ah, bh[nt], acc[nt], 0, 0, 0);
      acc[nt] = __builtin_amdgcn_mfma_f32_16x16x32_bf16(ah, bl[nt], acc[nt], 0, 0, 0);
      acc[nt] = __builtin_amdgcn_mfma_f32_16x16x32_bf16(al, bh[nt], acc[nt], 0, 0, 0);
    }
  };
  LD(0, ah0, al0, bh0, bl0);
  LD(1, ah1, al1, bh1, bl1);
  ST(ah0, al0, bh0, bl0);
  LD(2, ah0, al0, bh0, bl0);
  ST(ah1, al1, bh1, bl1);
  LD(3, ah1, al1, bh1, bl1);
  ST(ah0, al0, bh0, bl0);
  ST(ah1, al1, bh1, bl1);
  float* Gs = G + ((size_t)s << 20);
  int qrow = mt * 16 + lg * 4;
#pragma unroll
  for (int nt = 0; nt < 4; ++nt) {
    int p0 = ngg * 64 + nt * 16 + lr;
#pragma unroll
    for (int r = 0; r < 4; ++r)
      Gs[(size_t)(qrow + r) * LL + p0] = acc[nt][r];
  }
}

// ---------------- sbuildT v3: 4 q per block (same qh), 18-row shared stage.
__global__ __launch_bounds__(256) void sbuildT(const float* __restrict__ Gt,
                                               const float* __restrict__ nrm,
                                               float* __restrict__ St) {
  int g = blockIdx.x;              // 1024 = 4s * 32qh * 8qg
  int qg = g & 7, qh = (g >> 3) & 31, s = g >> 8;
  int qw0 = qg * 4;
  int t = threadIdx.x;
  __shared__ float L[18][1024];    // 72 KB
  const float* Gs = Gt + ((size_t)s << 20);
#pragma unroll
  for (int slot = 0; slot < 18; ++slot) {
    int dh = slot / 6 - 1, j = slot % 6;
    int qh2 = qh + dh, qw2 = qw0 - 1 + j;
    bool ok = ((unsigned)qh2 < 32u) && ((unsigned)qw2 < 32u);
    float4 val = ok ? *(const float4*)(Gs + ((size_t)(qh2 * 32 + qw2) << 10) + t * 4)
                    : make_float4(0.f, 0.f, 0.f, 0.f);
    *(float4*)&L[slot][t * 4] = val;
  }
  __syncthreads();
  const float* nr = nrm + s * LL;
#pragma unroll
  for (int ii = 0; ii < 4; ++ii) {
    int p = ii * 256 + t;
    int ph = p >> 5, pw = p & 31;
    float nrp = nr[p];
#pragma unroll
    for (int qq = 0; qq < 4; ++qq) {
      float acc = 0.f;
#pragma unroll
      for (int dh = -1; dh <= 1; ++dh)
#pragma unroll
        for (int dw = -1; dw <= 1; ++dw) {
          int ph2 = ph + dh, pw2 = pw + dw;
          if ((unsigned)ph2 < 32u && (unsigned)pw2 < 32u)
            acc += L[(dh + 1) * 6 + qq + dw + 1][p + dh * 32 + dw];
        }
      St[((size_t)s << 20) + ((size_t)(qh * 32 + qw0 + qq) << 10) + p] = acc / nrp;
    }
  }
}

// ---------------- fuse12_softmax v3: 4 q per block, 18-row shared stage,
// per-row softmax over p with block reduction.
__global__ __launch_bounds__(256) void fuse12_softmax(const float* __restrict__ St,
                                                      const float* __restrict__ mmv,
                                                      float* __restrict__ yiT) {
  int g = blockIdx.x;              // 1024 = 4s * 32qh * 8qg
  int qg = g & 7, qh = (g >> 3) & 31, s = g >> 8;
  int qw0 = qg * 4;
  int q0 = qh * 32 + qw0;
  int t = threadIdx.x;
  int lane = t & 63, wv = t >> 6;
  __shared__ float L[18][1024];    // 72 KB
  __shared__ float redA[4][4];
  __shared__ float redB[4][4];
  const float* Ss = St + ((size_t)s << 20);
  const float* mm = mmv + s * LL;
  int base[3];
  base[0] = (qh > 0) ? (q0 - 33) : (992 + qw0 - 2);
  base[1] = q0 - 1;
  base[2] = (qh < 31) ? (q0 + 31) : qw0;
#pragma unroll
  for (int slot = 0; slot < 18; ++slot) {
    int d2 = slot / 6, j = slot % 6;
    int row = base[d2] + j;
    bool ok = (unsigned)row < 1024u;
    float4 val = ok ? *(const float4*)(Ss + ((size_t)row << 10) + t * 4)
                    : make_float4(0.f, 0.f, 0.f, 0.f);
    *(float4*)&L[slot][t * 4] = val;
  }
  __syncthreads();
  bool vq0[4], vq2[4];
#pragma unroll
  for (int qq = 0; qq < 4; ++qq) {
    int qw = qw0 + qq;
    vq0[qq] = !(qh == 0 && qw == 0);
    vq2[qq] = !(qh == 31 && qw == 31);
  }
  float v[4][4];
  float mval[4];
  float mxq[4] = {-1e30f, -1e30f, -1e30f, -1e30f};
#pragma unroll
  for (int ii = 0; ii < 4; ++ii) {
    int p = ii * 256 + t;
    int ph = p >> 5, pw = p & 31;
    int rp[3]; bool vp[3];
    if (ph > 0)      { rp[0] = p - 32;        vp[0] = true; }
    else if (pw > 0) { rp[0] = 992 + pw - 1;  vp[0] = true; }
    else             { rp[0] = 0;             vp[0] = false; }
    rp[1] = p; vp[1] = true;
    if (ph < 31)      { rp[2] = p + 32;   vp[2] = true; }
    else if (pw < 31) { rp[2] = pw + 1;   vp[2] = true; }
    else              { rp[2] = 0;        vp[2] = false; }
    mval[ii] = mm[p];
#pragma unroll
    for (int qq = 0; qq < 4; ++qq) {
      float acc = 0.f;
#pragma unroll
      for (int d2 = 0; d2 < 3; ++d2) {
        bool vq = (d2 == 0) ? vq0[qq] : ((d2 == 2) ? vq2[qq] : true);
        if (vq && vp[d2]) {
#pragma unroll
          for (int d1 = -1; d1 <= 1; ++d1) {
            int cc = rp[d2] + d1;
            if ((unsigned)cc < 1024u)
              acc += L[d2 * 6 + qq + d1 + 1][cc];
          }
        }
      }
      float val = acc * mval[ii] * 10.f;
      v[ii][qq] = val;
      mxq[qq] = fmaxf(mxq[qq], val);
    }
  }
#pragma unroll
  for (int qq = 0; qq < 4; ++qq) {
    float m = mxq[qq];
#pragma unroll
    for (int o = 32; o; o >>= 1) m = fmaxf(m, __shfl_xor(m, o));
    if (lane == 0) redA[wv][qq] = m;
  }
  __syncthreads();
  float fm[4], sq[4] = {0.f, 0.f, 0.f, 0.f};
#pragma unroll
  for (int qq = 0; qq < 4; ++qq)
    fm[qq] = fmaxf(fmaxf(redA[0][qq], redA[1][qq]), fmaxf(redA[2][qq], redA[3][qq]));
#pragma unroll
  for (int ii = 0; ii < 4; ++ii)
#pragma unroll
    for (int qq = 0; qq < 4; ++qq) {
      v[ii][qq] = __expf(v[ii][qq] - fm[qq]);
      sq[qq] += v[ii][qq];
    }
#pragma unroll
  for (int qq = 0; qq < 4; ++qq) {
    float sm = sq[qq];
#pragma unroll
    for (int o = 32; o; o >>= 1) sm += __shfl_xor(sm, o);
    if (lane == 0) redB[wv][qq] = sm;
  }
  __syncthreads();
  float inv[4];
#pragma unroll
  for (int qq = 0; qq < 4; ++qq)
    inv[qq] = 1.f / ((redB[0][qq] + redB[1][qq]) + (redB[2][qq] + redB[3][qq]));
#pragma unroll
  for (int qq = 0; qq < 4; ++qq) {
    float* yo = yiT + ((size_t)s << 20) + ((size_t)(q0 + qq) << 10);
#pragma unroll
    for (int ii = 0; ii < 4; ++ii) {
      int p = ii * 256 + t;
      yo[p] = v[ii][qq] * inv[qq] * mval[ii];
    }
  }
}

// ---------------- build P (4-tap diagonal sums of yiT) as bf16; one block per
// (s, ih, 4-jw strip): 18-row LDS stage shared by 4 n x 4 cls outputs
__global__ __launch_bounds__(256) void build_p(const float* __restrict__ yiT,
                                               u16* __restrict__ Pb) {
  int bx = blockIdx.x;               // 1024 = 4s * 32ih * 8jg
  int jg = bx & 7, ih = (bx >> 3) & 31, s = bx >> 8;
  int jw0 = jg * 4;
  const float* Y = yiT + ((size_t)s << 20);
  __shared__ float R[18][1024];      // [di*6+jj][k]
  int t = threadIdx.x;
#pragma unroll
  for (int r = 0; r < 18; ++r) {
    int di = r / 6, jj = r % 6;
    int ihh = ih + di - 1, jww = jw0 + jj - 1;
    bool vld = ((unsigned)ihh < 32u) && ((unsigned)jww < 32u);
    float4 val = vld ? *(const float4*)(Y + ((size_t)(ihh * 32 + jww) << 10) + t * 4)
                     : make_float4(0.f, 0.f, 0.f, 0.f);
    *(float4*)&R[r][t * 4] = val;
  }
  __syncthreads();
  int nl = t >> 6, lane = t & 63;
  int n = ih * 32 + jw0 + nl;
#pragma unroll
  for (int kq = 0; kq < 4; ++kq) {
    int k0 = (kq * 64 + lane) * 4;
    int kh = k0 >> 5;
#pragma unroll
    for (int cls = 0; cls < 4; ++cls) {
      int py = cls >> 1, px = cls & 1;
      int sy = py ? 1 : -1, sx = px ? 1 : -1;
      const float* RA = R[6 + nl + 1];
      const float* RB = R[(1 + sy) * 6 + nl + 1];
      const float* RC = R[6 + nl + 1 + sx];
      const float* RD = R[(1 + sy) * 6 + nl + 1 + sx];
      bool mB = (unsigned)(kh + sy) < 32u;
      int ob = 32 * sy;
      u16x4 pk;
#pragma unroll
      for (int e = 0; e < 4; ++e) {
        int k = k0 + e, kw = k & 31;
        bool mC = (unsigned)(kw + sx) < 32u;
        float v = RA[k];
        if (mB) v += RB[k + ob];
        if (mC) v += RC[k + sx];
        if (mB && mC) v += RD[k + ob + sx];
        pk[e] = f2bf(v);
      }
      int zz = s * 4 + cls;
      *(u16x4*)(Pb + (((size_t)(zz * LL + n)) << 10) + k0) = pk;
    }
  }
}

// ---------------- deconv GEMM v4: wave = 32c x 64n, block = 4 waves (64c x 128n),
// grid 256 = 16z * 2cb * 8nb, depth-6 register prefetch, K=1024
#define DGLD(i, kc) { int o = (kc) * 32;                      \
    A##i##0 = *(const s16x8*)(Ap0 + o);                       \
    A##i##1 = *(const s16x8*)(Ap1 + o);                       \
    B##i##0 = *(const s16x8*)(Bp0 + o);                       \
    B##i##1 = *(const s16x8*)(Bp1 + o);                       \
    B##i##2 = *(const s16x8*)(Bp2 + o);                       \
    B##i##3 = *(const s16x8*)(Bp3 + o); }
#define DGST(i) {                                                                     \
    acc[0][0] = __builtin_amdgcn_mfma_f32_16x16x32_bf16(A##i##0, B##i##0, acc[0][0], 0, 0, 0); \
    acc[0][1] = __builtin_amdgcn_mfma_f32_16x16x32_bf16(A##i##0, B##i##1, acc[0][1], 0, 0, 0); \
    acc[0][2] = __builtin_amdgcn_mfma_f32_16x16x32_bf16(A##i##0, B##i##2, acc[0][2], 0, 0, 0); \
    acc[0][3] = __builtin_amdgcn_mfma_f32_16x16x32_bf16(A##i##0, B##i##3, acc[0][3], 0, 0, 0); \
    acc[1][0] = __builtin_amdgcn_mfma_f32_16x16x32_bf16(A##i##1, B##i##0, acc[1][0], 0, 0, 0); \
    acc[1][1] = __builtin_amdgcn_mfma_f32_16x16x32_bf16(A##i##1, B##i##1, acc[1][1], 0, 0, 0); \
    acc[1][2] = __builtin_amdgcn_mfma_f32_16x16x32_bf16(A##i##1, B##i##2, acc[1][2], 0, 0, 0); \
    acc[1][3] = __builtin_amdgcn_mfma_f32_16x16x32_bf16(A##i##1, B##i##3, acc[1][3], 0, 0, 0); }

__global__ __launch_bounds__(256, 1) void deconv_gemm(const u16* __restrict__ Pb,
                                                      const u16* __restrict__ Wt,
                                                      float* __restrict__ out) {
  int bx = blockIdx.x;               // 256 = 16z * 2cb * 8nb
  int nb = bx & 7, cb = (bx >> 3) & 1, z = bx >> 4;
  int s = z >> 2, cls = z & 3, py = cls >> 1, px = cls & 1;
  int wz = threadIdx.x >> 6;
  int wc = wz >> 1, wn = wz & 1;
  int l = threadIdx.x & 63, lr = l & 15, lg = l >> 4;
  int c0 = cb * 64 + wc * 32;
  int n0 = nb * 128 + wn * 64;
  const u16* Ap0 = Wt + ((size_t)z * NC + c0 + lr) * LL + lg * 8;
  const u16* Ap1 = Ap0 + (size_t)16 * LL;
  const u16* Bp0 = Pb + ((size_t)(z * LL + n0 + lr)) * LL + lg * 8;
  const u16* Bp1 = Bp0 + (size_t)16 * LL;
  const u16* Bp2 = Bp0 + (size_t)32 * LL;
  const u16* Bp3 = Bp0 + (size_t)48 * LL;
  f32x4 acc[2][4] = {};
  s16x8 A00, A01, B00, B01, B02, B03;
  s16x8 A10, A11, B10, B11, B12, B13;
  s16x8 A20, A21, B20, B21, B22, B23;
  s16x8 A30, A31, B30, B31, B32, B33;
  s16x8 A40, A41, B40, B41, B42, B43;
  s16x8 A50, A51, B50, B51, B52, B53;
  DGLD(0, 0) DGLD(1, 1) DGLD(2, 2) DGLD(3, 3) DGLD(4, 4) DGLD(5, 5)
#pragma unroll
  for (int kc = 0; kc < 30; kc += 6) {
    DGST(0) if (kc + 6  < 32) DGLD(0, kc + 6)
    DGST(1) if (kc + 7  < 32) DGLD(1, kc + 7)
    DGST(2) if (kc + 8  < 32) DGLD(2, kc + 8)
    DGST(3) if (kc + 9  < 32) DGLD(3, kc + 9)
    DGST(4) if (kc + 10 < 32) DGLD(4, kc + 10)
    DGST(5) if (kc + 11 < 32) DGLD(5, kc + 11)
  }
  DGST(0) DGST(1)                  // kc = 30, 31
  float* os = out + (size_t)s * NC * HH * WW;
#pragma unroll
  for (int mt = 0; mt < 2; ++mt) {
    int cc = c0 + mt * 16 + lg * 4;
#pragma unroll
    for (int nt = 0; nt < 4; ++nt) {
      int nn = n0 + nt * 16 + lr;
      size_t ob = (size_t)(2 * (nn >> 5) + py) * WW + 2 * (nn & 31) + px;
#pragma unroll
      for (int r = 0; r < 4; ++r)
        os[(size_t)(cc + r) * (HH * WW) + ob] = acc[mt][nt][r] * 0.25f;
    }
  }
}

extern "C" void kernel_launch(void* const* d_in, const int* in_sizes, int n_in,
                              void* d_out, int out_size, void* d_ws, size_t ws_size,
                              hipStream_t stream) {
  const float* f    = (const float*)d_in[0];
  const float* b    = (const float*)d_in[1];
  const float* mask = (const float*)d_in[2];
  float* out  = (float*)d_out;

  // workspace layout: ~74 MB
  float* buf0 = (float*)d_ws;              // 4,194,304 f (Gt -> yiT)
  float* buf1 = buf0 + 4194304;            // 4,194,304 f (St)
  u16* bsT_hi = (u16*)(buf1 + 4194304);    // 524,288 u16 each
  u16* bsT_lo = bsT_hi + 524288;
  u16* fsT_hi = bsT_lo + 524288;
  u16* fsT_lo = fsT_hi + 524288;
  u16* Wt     = fsT_lo + 524288;           // 2,097,152 u16
  float* Qp   = (float*)(Wt + 2097152);    // 8,192 (2 partials)
  float* nrm  = Qp + 8192;                 // 4,096
  float* mmv  = nrm + 4096;                // 4,096
  u16* Pb     = (u16*)(mmv + 4096);        // 16,777,216 u16 (32 MB, all 16 z)

  hipLaunchKernelGGL(prep, dim3(256), dim3(256), 0, stream, f, b, bsT_hi, bsT_lo, fsT_hi, fsT_lo, Qp);
  hipLaunchKernelGGL(prep_wt, dim3(2048), dim3(256), 0, stream, b, Wt);
  hipLaunchKernelGGL(aux_nrm, dim3(4), dim3(1024), 0, stream, Qp, mask, nrm, mmv);
  hipLaunchKernelGGL(gram_mfma, dim3(1024), dim3(256), 0, stream, fsT_hi, fsT_lo, bsT_hi, bsT_lo, buf0);
  hipLaunchKernelGGL(sbuildT, dim3(1024), dim3(256), 0, stream, buf0, nrm, buf1);
  hipLaunchKernelGGL(fuse12_softmax, dim3(1024), dim3(256), 0, stream, buf1, mmv, buf0);
  hipLaunchKernelGGL(build_p, dim3(1024), dim3(256), 0, stream, buf0, Pb);
  hipLaunchKernelGGL(deconv_gemm, dim3(256), dim3(256), 0, stream, Pb, Wt, out);
}

// Round 11
// 125.477 us; speedup vs baseline: 1.0790x; 1.0737x over previous
//
#include <hip/hip_runtime.h>
#include <math.h>

#define NS 4
#define NC 128
#define HH 64
#define WW 64
#define LL 1024   // 32*32

typedef unsigned short u16;
typedef u16 u16x4 __attribute__((ext_vector_type(4)));
typedef short s16x8 __attribute__((ext_vector_type(8)));
typedef float f32x4 __attribute__((ext_vector_type(4)));

__device__ __forceinline__ u16 f2bf(float x) {
  unsigned u = __float_as_uint(x);
  return (u16)((u + 0x7FFFu + ((u >> 16) & 1u)) >> 16);
}
__device__ __forceinline__ float bf2f(u16 h) {
  return __uint_as_float(((unsigned)h) << 16);
}
__device__ __forceinline__ void gload16(const u16* g, u16* l) {
  __builtin_amdgcn_global_load_lds((const __attribute__((address_space(1))) void*)g,
                                   (__attribute__((address_space(3))) void*)l, 16, 0, 0);
}

// ---------------- K1: prep (256 blocks) + prep_wt (2048 blocks) in one launch
__global__ __launch_bounds__(256) void prep_all(const float* __restrict__ f,
                                                const float* __restrict__ b,
                                                u16* __restrict__ bsT_hi, u16* __restrict__ bsT_lo,
                                                u16* __restrict__ fsT_hi, u16* __restrict__ fsT_lo,
                                                float* __restrict__ Qp,
                                                u16* __restrict__ Wt) {
  int bx = blockIdx.x;
  int t = threadIdx.x;
  __shared__ float Lb[32][68];
  __shared__ float Lf[32][68];
  __shared__ float SS[256];
  if (bx < 256) {
    // ---- prep path: 256 = 4s * 32qh * 2cg
    int cg = bx & 1, qh = (bx >> 1) & 31, s = bx >> 6;
    const float* brow = b + ((size_t)(s * NC + cg * 64) * HH + 2 * qh) * WW;
    const float* frow = f + ((size_t)(s * NC + cg * 64) * HH + 2 * qh) * WW;
#pragma unroll
    for (int i = 0; i < 4; ++i) {
      int task = i * 256 + t;
      int c = task >> 4, j = task & 15;
      float4 vb = *(const float4*)(brow + (size_t)c * (HH * WW) + 4 * j);
      float4 vf = *(const float4*)(frow + (size_t)c * (HH * WW) + 4 * j);
      Lb[2 * j][c] = vb.x; Lb[2 * j + 1][c] = vb.z;
      Lf[2 * j][c] = vf.x; Lf[2 * j + 1][c] = vf.z;
    }
    __syncthreads();
    int qw = t >> 3, og = t & 7;
    int col = og * 8;
    int q = qh * 32 + qw;
    float ssq = 0.f;
    s16x8 vbh, vbl, vfh, vfl;
#pragma unroll
    for (int e = 0; e < 8; ++e) {
      float xb = Lb[qw][col + e], xf = Lf[qw][col + e];
      ssq += xb * xb;
      u16 hb = f2bf(xb); u16 lb = f2bf(xb - bf2f(hb));
      u16 hf = f2bf(xf); u16 lf = f2bf(xf - bf2f(hf));
      vbh[e] = (short)hb; vbl[e] = (short)lb; vfh[e] = (short)hf; vfl[e] = (short)lf;
    }
    size_t o = ((size_t)(s * LL) + q) * NC + cg * 64 + col;
    *(s16x8*)(bsT_hi + o) = vbh;
    *(s16x8*)(bsT_lo + o) = vbl;
    *(s16x8*)(fsT_hi + o) = vfh;
    *(s16x8*)(fsT_lo + o) = vfl;
    SS[t] = ssq;
    __syncthreads();
    if (og == 0) {
      float sum = 0.f;
#pragma unroll
      for (int j = 0; j < 8; ++j) sum += SS[qw * 8 + j];
      Qp[cg * (NS * LL) + s * LL + q] = sum;
    }
  } else {
    // ---- prep_wt path: 2048 = 4s * 128c * 4khg
    int b2 = bx - 256;
    int khg = b2 & 3, c = (b2 >> 2) & 127, s = b2 >> 9;
    float (*Lw)[68] = Lb;          // reuse shared
    const float* src = b + ((size_t)(s * NC + c) * HH + 16 * khg) * WW;
    float4 v = *(const float4*)(src + (t >> 4) * WW + (t & 15) * 4);
    int rr = t >> 4, qq4 = (t & 15) * 4;
    Lw[rr][qq4] = v.x; Lw[rr][qq4 + 1] = v.y; Lw[rr][qq4 + 2] = v.z; Lw[rr][qq4 + 3] = v.w;
    __syncthreads();
    if (t < 128) {
      int cls = t >> 5, kh_l = (t >> 2) & 7, ko = t & 3;
      int py = cls >> 1, px = cls & 1;
      int y = 2 * kh_l + py;
      s16x8 w;
#pragma unroll
      for (int e = 0; e < 8; ++e) w[e] = (short)f2bf(Lw[y][16 * ko + 2 * e + px]);
      int kh = khg * 8 + kh_l;
      int z = s * 4 + cls;
      *(s16x8*)(Wt + (((size_t)(z * NC + c)) << 10) + kh * 32 + 8 * ko) = w;
    }
  }
}

// ---------------- K2: Gt[q][p] = sum_c fs[c][q]*bs[c][p], split-bf16 MFMA
__global__ __launch_bounds__(256) void gram_mfma(const u16* __restrict__ aT_hi,
                                                 const u16* __restrict__ aT_lo,
                                                 const u16* __restrict__ bT_hi,
                                                 const u16* __restrict__ bT_lo,
                                                 float* __restrict__ G) {
  int wid = blockIdx.x * 4 + (threadIdx.x >> 6);  // 4096 = 4s * 64mt * 16ngg
  int ngg = wid & 15, mt = (wid >> 4) & 63, s = wid >> 10;
  int l = threadIdx.x & 63, lr = l & 15, lg = l >> 4;
  const u16* Ah = aT_hi + ((size_t)(s * LL) + mt * 16 + lr) * NC + lg * 8;
  const u16* Al = aT_lo + ((size_t)(s * LL) + mt * 16 + lr) * NC + lg * 8;
  size_t bbase = ((size_t)(s * LL) + ngg * 64 + lr) * NC + lg * 8;
  f32x4 acc[4] = {};
  s16x8 ah0, al0, bh0[4], bl0[4];
  s16x8 ah1, al1, bh1[4], bl1[4];
  auto LD = [&](int kc, s16x8& ah, s16x8& al, s16x8* bh, s16x8* bl) {
    int o = kc * 32;
    ah = *(const s16x8*)(Ah + o);
    al = *(const s16x8*)(Al + o);
#pragma unroll
    for (int nt = 0; nt < 4; ++nt) {
      bh[nt] = *(const s16x8*)(bT_hi + bbase + nt * 16 * NC + o);
      bl[nt] = *(const s16x8*)(bT_lo + bbase + nt * 16 * NC + o);
    }
  };
  auto ST = [&](s16x8& ah, s16x8& al, s16x8* bh, s16x8* bl) {
#pragma unroll
    for (int nt = 0; nt < 4; ++nt) {
      acc[nt] = __builtin_amdgcn_mfma_f32_16x16x32_bf16(ah, bh[nt], acc[nt], 0, 0, 0);
      acc[nt] = __builtin_amdgcn_mfma_f32_16x16x32_bf16(ah, bl[nt], acc[nt], 0, 0, 0);
      acc[nt] = __builtin_amdgcn_mfma_f32_16x16x32_bf16(al, bh[nt], acc[nt], 0, 0, 0);
    }
  };
  LD(0, ah0, al0, bh0, bl0);
  LD(1, ah1, al1, bh1, bl1);
  ST(ah0, al0, bh0, bl0);
  LD(2, ah0, al0, bh0, bl0);
  ST(ah1, al1, bh1, bl1);
  LD(3, ah1, al1, bh1, bl1);
  ST(ah0, al0, bh0, bl0);
  ST(ah1, al1, bh1, bl1);
  float* Gs = G + ((size_t)s << 20);
  int qrow = mt * 16 + lg * 4;
#pragma unroll
  for (int nt = 0; nt < 4; ++nt) {
    int p0 = ngg * 64 + nt * 16 + lr;
#pragma unroll
    for (int r = 0; r < 4; ++r)
      Gs[(size_t)(qrow + r) * LL + p0] = acc[nt][r];
  }
}

// ---------------- K3: sbuildT + nrm folded (4 q/block, 18-row stage, Q staged)
__global__ __launch_bounds__(256) void sbuildT(const float* __restrict__ Gt,
                                               const float* __restrict__ Qp,
                                               float* __restrict__ St) {
  int g = blockIdx.x;              // 1024 = 4s * 32qh * 8qg
  int qg = g & 7, qh = (g >> 3) & 31, s = g >> 8;
  int qw0 = qg * 4;
  int t = threadIdx.x;
  __shared__ float L[18][1024];    // 72 KB
  __shared__ float Qrow[1024];
  const float* Gs = Gt + ((size_t)s << 20);
  {
    int p4 = t * 4;
    float4 a = *(const float4*)(Qp + s * LL + p4);
    float4 c = *(const float4*)(Qp + NS * LL + s * LL + p4);
    float4 r = make_float4(a.x + c.x, a.y + c.y, a.z + c.z, a.w + c.w);
    *(float4*)&Qrow[p4] = r;
  }
#pragma unroll
  for (int slot = 0; slot < 18; ++slot) {
    int dh = slot / 6 - 1, j = slot % 6;
    int qh2 = qh + dh, qw2 = qw0 - 1 + j;
    bool ok = ((unsigned)qh2 < 32u) && ((unsigned)qw2 < 32u);
    float4 val = ok ? *(const float4*)(Gs + ((size_t)(qh2 * 32 + qw2) << 10) + t * 4)
                    : make_float4(0.f, 0.f, 0.f, 0.f);
    *(float4*)&L[slot][t * 4] = val;
  }
  __syncthreads();
#pragma unroll
  for (int ii = 0; ii < 4; ++ii) {
    int p = ii * 256 + t;
    int ph = p >> 5, pw = p & 31;
    float sum2 = 1152 * 1e-4f;
#pragma unroll
    for (int dh = -1; dh <= 1; ++dh)
#pragma unroll
      for (int dw = -1; dw <= 1; ++dw) {
        int h = ph + dh, w = pw + dw;
        if ((unsigned)h < 32u && (unsigned)w < 32u) sum2 += Qrow[h * 32 + w];
      }
    float nrp = sqrtf(sum2);
#pragma unroll
    for (int qq = 0; qq < 4; ++qq) {
      float acc = 0.f;
#pragma unroll
      for (int dh = -1; dh <= 1; ++dh)
#pragma unroll
        for (int dw = -1; dw <= 1; ++dw) {
          int ph2 = ph + dh, pw2 = pw + dw;
          if ((unsigned)ph2 < 32u && (unsigned)pw2 < 32u)
            acc += L[(dh + 1) * 6 + qq + dw + 1][p + dh * 32 + dw];
        }
      St[((size_t)s << 20) + ((size_t)(qh * 32 + qw0 + qq) << 10) + p] = acc / nrp;
    }
  }
}

// ---------------- K4: fuse12 + softmax + mask-mean folded
__global__ __launch_bounds__(256) void fuse12_softmax(const float* __restrict__ St,
                                                      const float* __restrict__ mask,
                                                      float* __restrict__ yiT) {
  int g = blockIdx.x;              // 1024 = 4s * 32qh * 8qg
  int qg = g & 7, qh = (g >> 3) & 31, s = g >> 8;
  int qw0 = qg * 4;
  int q0 = qh * 32 + qw0;
  int t = threadIdx.x;
  int lane = t & 63, wv = t >> 6;
  __shared__ float L[18][1024];    // 72 KB
  __shared__ float Mrow[1024];
  __shared__ float redA[4][4];
  __shared__ float redB[4][4];
  const float* Ss = St + ((size_t)s << 20);
  {
    int p4 = t * 4;
    const float* mrow = mask + s * HH * WW + ((p4 >> 5) * 2) * WW + (p4 & 31) * 2;
    float4 a = *(const float4*)mrow;
    float4 c = *(const float4*)(mrow + 4);
    *(float4*)&Mrow[p4] = make_float4(a.x, a.z, c.x, c.z);
  }
  int base[3];
  base[0] = (qh > 0) ? (q0 - 33) : (992 + qw0 - 2);
  base[1] = q0 - 1;
  base[2] = (qh < 31) ? (q0 + 31) : qw0;
#pragma unroll
  for (int slot = 0; slot < 18; ++slot) {
    int d2 = slot / 6, j = slot % 6;
    int row = base[d2] + j;
    bool ok = (unsigned)row < 1024u;
    float4 val = ok ? *(const float4*)(Ss + ((size_t)row << 10) + t * 4)
                    : make_float4(0.f, 0.f, 0.f, 0.f);
    *(float4*)&L[slot][t * 4] = val;
  }
  __syncthreads();
  bool vq0[4], vq2[4];
#pragma unroll
  for (int qq = 0; qq < 4; ++qq) {
    int qw = qw0 + qq;
    vq0[qq] = !(qh == 0 && qw == 0);
    vq2[qq] = !(qh == 31 && qw == 31);
  }
  float v[4][4];
  float mval[4];
  float mxq[4] = {-1e30f, -1e30f, -1e30f, -1e30f};
#pragma unroll
  for (int ii = 0; ii < 4; ++ii) {
    int p = ii * 256 + t;
    int ph = p >> 5, pw = p & 31;
    // mask mean (exact aux_nrm formula)
    float msum = 0.f;
#pragma unroll
    for (int dh = -1; dh <= 1; ++dh)
#pragma unroll
      for (int dw = -1; dw <= 1; ++dw) {
        int h = ph + dh, w = pw + dw;
        if ((unsigned)h < 32u && (unsigned)w < 32u) msum += Mrow[h * 32 + w];
      }
    mval[ii] = msum * (1.f / 9.f);
    int rp[3]; bool vp[3];
    if (ph > 0)      { rp[0] = p - 32;        vp[0] = true; }
    else if (pw > 0) { rp[0] = 992 + pw - 1;  vp[0] = true; }
    else             { rp[0] = 0;             vp[0] = false; }
    rp[1] = p; vp[1] = true;
    if (ph < 31)      { rp[2] = p + 32;   vp[2] = true; }
    else if (pw < 31) { rp[2] = pw + 1;   vp[2] = true; }
    else              { rp[2] = 0;        vp[2] = false; }
#pragma unroll
    for (int qq = 0; qq < 4; ++qq) {
      float acc = 0.f;
#pragma unroll
      for (int d2 = 0; d2 < 3; ++d2) {
        bool vq = (d2 == 0) ? vq0[qq] : ((d2 == 2) ? vq2[qq] : true);
        if (vq && vp[d2]) {
#pragma unroll
          for (int d1 = -1; d1 <= 1; ++d1) {
            int cc = rp[d2] + d1;
            if ((unsigned)cc < 1024u)
              acc += L[d2 * 6 + qq + d1 + 1][cc];
          }
        }
      }
      float val = acc * mval[ii] * 10.f;
      v[ii][qq] = val;
      mxq[qq] = fmaxf(mxq[qq], val);
    }
  }
#pragma unroll
  for (int qq = 0; qq < 4; ++qq) {
    float m = mxq[qq];
#pragma unroll
    for (int o = 32; o; o >>= 1) m = fmaxf(m, __shfl_xor(m, o));
    if (lane == 0) redA[wv][qq] = m;
  }
  __syncthreads();
  float fm[4], sq[4] = {0.f, 0.f, 0.f, 0.f};
#pragma unroll
  for (int qq = 0; qq < 4; ++qq)
    fm[qq] = fmaxf(fmaxf(redA[0][qq], redA[1][qq]), fmaxf(redA[2][qq], redA[3][qq]));
#pragma unroll
  for (int ii = 0; ii < 4; ++ii)
#pragma unroll
    for (int qq = 0; qq < 4; ++qq) {
      v[ii][qq] = __expf(v[ii][qq] - fm[qq]);
      sq[qq] += v[ii][qq];
    }
#pragma unroll
  for (int qq = 0; qq < 4; ++qq) {
    float sm = sq[qq];
#pragma unroll
    for (int o = 32; o; o >>= 1) sm += __shfl_xor(sm, o);
    if (lane == 0) redB[wv][qq] = sm;
  }
  __syncthreads();
  float inv[4];
#pragma unroll
  for (int qq = 0; qq < 4; ++qq)
    inv[qq] = 1.f / ((redB[0][qq] + redB[1][qq]) + (redB[2][qq] + redB[3][qq]));
#pragma unroll
  for (int qq = 0; qq < 4; ++qq) {
    float* yo = yiT + ((size_t)s << 20) + ((size_t)(q0 + qq) << 10);
#pragma unroll
    for (int ii = 0; ii < 4; ++ii) {
      int p = ii * 256 + t;
      yo[p] = v[ii][qq] * inv[qq] * mval[ii];
    }
  }
}

// ---------------- K5: build P (4-tap diagonal sums of yiT) as bf16
__global__ __launch_bounds__(256) void build_p(const float* __restrict__ yiT,
                                               u16* __restrict__ Pb) {
  int bx = blockIdx.x;               // 1024 = 4s * 32ih * 8jg
  int jg = bx & 7, ih = (bx >> 3) & 31, s = bx >> 8;
  int jw0 = jg * 4;
  const float* Y = yiT + ((size_t)s << 20);
  __shared__ float R[18][1024];
  int t = threadIdx.x;
#pragma unroll
  for (int r = 0; r < 18; ++r) {
    int di = r / 6, jj = r % 6;
    int ihh = ih + di - 1, jww = jw0 + jj - 1;
    bool vld = ((unsigned)ihh < 32u) && ((unsigned)jww < 32u);
    float4 val = vld ? *(const float4*)(Y + ((size_t)(ihh * 32 + jww) << 10) + t * 4)
                     : make_float4(0.f, 0.f, 0.f, 0.f);
    *(float4*)&R[r][t * 4] = val;
  }
  __syncthreads();
  int nl = t >> 6, lane = t & 63;
  int n = ih * 32 + jw0 + nl;
#pragma unroll
  for (int kq = 0; kq < 4; ++kq) {
    int k0 = (kq * 64 + lane) * 4;
    int kh = k0 >> 5;
#pragma unroll
    for (int cls = 0; cls < 4; ++cls) {
      int py = cls >> 1, px = cls & 1;
      int sy = py ? 1 : -1, sx = px ? 1 : -1;
      const float* RA = R[6 + nl + 1];
      const float* RB = R[(1 + sy) * 6 + nl + 1];
      const float* RC = R[6 + nl + 1 + sx];
      const float* RD = R[(1 + sy) * 6 + nl + 1 + sx];
      bool mB = (unsigned)(kh + sy) < 32u;
      int ob = 32 * sy;
      u16x4 pk;
#pragma unroll
      for (int e = 0; e < 4; ++e) {
        int k = k0 + e, kw = k & 31;
        bool mC = (unsigned)(kw + sx) < 32u;
        float v = RA[k];
        if (mB) v += RB[k + ob];
        if (mC) v += RC[k + sx];
        if (mB && mC) v += RD[k + ob + sx];
        pk[e] = f2bf(v);
      }
      int zz = s * 4 + cls;
      *(u16x4*)(Pb + (((size_t)(zz * LL + n)) << 10) + k0) = pk;
    }
  }
}

// ---------------- K6: deconv GEMM v5 — m97-style global_load_lds double-buffer.
// block = 4 waves = 64c x 128n; BK=64; grid 256 = 16z*2cb*8nb; swizzled LDS.
__global__ __launch_bounds__(256, 1) void deconv_gemm(const u16* __restrict__ Pb,
                                                      const u16* __restrict__ Wt,
                                                      float* __restrict__ out) {
  int bx = blockIdx.x;
  int nb = bx & 7, cb = (bx >> 3) & 1, z = bx >> 4;
  int s = z >> 2, cls = z & 3, py = cls >> 1, px = cls & 1;
  int t = threadIdx.x, w = t >> 6, l = t & 63, lr = l & 15, lg = l >> 4;
  int wc = w >> 1, wn = w & 1;
  int c0 = cb * 64, n0 = nb * 128;
  __shared__ __align__(16) u16 SA[2][64 * 64];    // 8 KB per buf
  __shared__ __align__(16) u16 SB[2][128 * 64];   // 16 KB per buf
  const u16* Ag = Wt + ((size_t)(z * NC + c0)) * LL;
  const u16* Bg = Pb + ((size_t)(z * LL + n0)) * LL;
  int rA  = l >> 3;                       // row within 8-row chunk
  int swz = ((l & 7) ^ (rA & 7)) * 8;     // pre-swizzled source octet (elems)

  auto STAGE = [&](int buf, int k0) {
#pragma unroll
    for (int j = 0; j < 6; ++j) {
      int ci = w * 6 + j;                 // 0..23
      if (ci < 8) {
        const u16* src = Ag + ((size_t)(ci * 8 + rA)) * LL + k0 + swz;
        gload16(src, &SA[buf][ci * 512]);
      } else {
        int cj = ci - 8;
        const u16* src = Bg + ((size_t)(cj * 8 + rA)) * LL + k0 + swz;
        gload16(src, &SB[buf][cj * 512]);
      }
    }
  };
#define ARD(r, o) (*(const s16x8*)((const char*)&SA[buf][0] + (r) * 128 + (((o) * 16) ^ (((r) & 7) << 4))))
#define BRD(r, o) (*(const s16x8*)((const char*)&SB[buf][0] + (r) * 128 + (((o) * 16) ^ (((r) & 7) << 4))))

  f32x4 acc[2][4] = {};
  int buf = 0;
  STAGE(0, 0);
#pragma unroll 1
  for (int it = 0; it < 16; ++it) {
    __syncthreads();                      // staged tile visible (vmcnt drained)
    if (it < 15) STAGE(buf ^ 1, (it + 1) * 64);
#pragma unroll
    for (int ks = 0; ks < 2; ++ks) {
      int o = ks * 4 + lg;
      s16x8 a0 = ARD(wc * 32 + lr, o);
      s16x8 a1 = ARD(wc * 32 + 16 + lr, o);
      s16x8 b0 = BRD(wn * 64 + lr, o);
      s16x8 b1 = BRD(wn * 64 + 16 + lr, o);
      s16x8 b2 = BRD(wn * 64 + 32 + lr, o);
      s16x8 b3 = BRD(wn * 64 + 48 + lr, o);
      acc[0][0] = __builtin_amdgcn_mfma_f32_16x16x32_bf16(a0, b0, acc[0][0], 0, 0, 0);
      acc[0][1] = __builtin_amdgcn_mfma_f32_16x16x32_bf16(a0, b1, acc[0][1], 0, 0, 0);
      acc[0][2] = __builtin_amdgcn_mfma_f32_16x16x32_bf16(a0, b2, acc[0][2], 0, 0, 0);
      acc[0][3] = __builtin_amdgcn_mfma_f32_16x16x32_bf16(a0, b3, acc[0][3], 0, 0, 0);
      acc[1][0] = __builtin_amdgcn_mfma_f32_16x16x32_bf16(a1, b0, acc[1][0], 0, 0, 0);
      acc[1][1] = __builtin_amdgcn_mfma_f32_16x16x32_bf16(a1, b1, acc[1][1], 0, 0, 0);
      acc[1][2] = __builtin_amdgcn_mfma_f32_16x16x32_bf16(a1, b2, acc[1][2], 0, 0, 0);
      acc[1][3] = __builtin_amdgcn_mfma_f32_16x16x32_bf16(a1, b3, acc[1][3], 0, 0, 0);
    }
    __syncthreads();                      // all reads done before next-stage write lands? (writes to buf^1 only; this guards buf reuse 2 iters later)
    buf ^= 1;
  }
  float* os = out + (size_t)s * NC * HH * WW;
#pragma unroll
  for (int mt = 0; mt < 2; ++mt) {
    int cc = c0 + wc * 32 + mt * 16 + lg * 4;
#pragma unroll
    for (int nt = 0; nt < 4; ++nt) {
      int nn = n0 + wn * 64 + nt * 16 + lr;
      size_t ob = (size_t)(2 * (nn >> 5) + py) * WW + 2 * (nn & 31) + px;
#pragma unroll
      for (int r = 0; r < 4; ++r)
        os[(size_t)(cc + r) * (HH * WW) + ob] = acc[mt][nt][r] * 0.25f;
    }
  }
#undef ARD
#undef BRD
}

extern "C" void kernel_launch(void* const* d_in, const int* in_sizes, int n_in,
                              void* d_out, int out_size, void* d_ws, size_t ws_size,
                              hipStream_t stream) {
  const float* f    = (const float*)d_in[0];
  const float* b    = (const float*)d_in[1];
  const float* mask = (const float*)d_in[2];
  float* out  = (float*)d_out;

  float* buf0 = (float*)d_ws;              // Gt -> yiT
  float* buf1 = buf0 + 4194304;            // St
  u16* bsT_hi = (u16*)(buf1 + 4194304);
  u16* bsT_lo = bsT_hi + 524288;
  u16* fsT_hi = bsT_lo + 524288;
  u16* fsT_lo = fsT_hi + 524288;
  u16* Wt     = fsT_lo + 524288;           // 2,097,152 u16
  float* Qp   = (float*)(Wt + 2097152);    // 8,192
  u16* Pb     = (u16*)(Qp + 8192);         // 16,777,216 u16 (32 MB)

  hipLaunchKernelGGL(prep_all, dim3(2304), dim3(256), 0, stream, f, b, bsT_hi, bsT_lo, fsT_hi, fsT_lo, Qp, Wt);
  hipLaunchKernelGGL(gram_mfma, dim3(1024), dim3(256), 0, stream, fsT_hi, fsT_lo, bsT_hi, bsT_lo, buf0);
  hipLaunchKernelGGL(sbuildT, dim3(1024), dim3(256), 0, stream, buf0, Qp, buf1);
  hipLaunchKernelGGL(fuse12_softmax, dim3(1024), dim3(256), 0, stream, buf1, mask, buf0);
  hipLaunchKernelGGL(build_p, dim3(1024), dim3(256), 0, stream, buf0, Pb);
  hipLaunchKernelGGL(deconv_gemm, dim3(256), dim3(256), 0, stream, Pb, Wt, out);
}

// Round 12
// 119.481 us; speedup vs baseline: 1.1332x; 1.0502x over previous
//
#include <hip/hip_runtime.h>
#include <math.h>

#define NS 4
#define NC 128
#define HH 64
#define WW 64
#define LL 1024   // 32*32

typedef unsigned short u16;
typedef u16 u16x4 __attribute__((ext_vector_type(4)));
typedef short s16x8 __attribute__((ext_vector_type(8)));
typedef float f32x4 __attribute__((ext_vector_type(4)));

__device__ __forceinline__ u16 f2bf(float x) {
  unsigned u = __float_as_uint(x);
  return (u16)((u + 0x7FFFu + ((u >> 16) & 1u)) >> 16);
}
__device__ __forceinline__ float bf2f(u16 h) {
  return __uint_as_float(((unsigned)h) << 16);
}
__device__ __forceinline__ void gload16(const void* g, void* l) {
  __builtin_amdgcn_global_load_lds((const __attribute__((address_space(1))) void*)g,
                                   (__attribute__((address_space(3))) void*)l, 16, 0, 0);
}

// ---------------- K1: prep (256 blocks) + prep_wt (2048 blocks) in one launch
__global__ __launch_bounds__(256) void prep_all(const float* __restrict__ f,
                                                const float* __restrict__ b,
                                                u16* __restrict__ bsT_hi, u16* __restrict__ bsT_lo,
                                                u16* __restrict__ fsT_hi, u16* __restrict__ fsT_lo,
                                                float* __restrict__ Qp,
                                                u16* __restrict__ Wt) {
  int bx = blockIdx.x;
  int t = threadIdx.x;
  __shared__ float Lb[32][68];
  __shared__ float Lf[32][68];
  __shared__ float SS[256];
  if (bx < 256) {
    int cg = bx & 1, qh = (bx >> 1) & 31, s = bx >> 6;
    const float* brow = b + ((size_t)(s * NC + cg * 64) * HH + 2 * qh) * WW;
    const float* frow = f + ((size_t)(s * NC + cg * 64) * HH + 2 * qh) * WW;
#pragma unroll
    for (int i = 0; i < 4; ++i) {
      int task = i * 256 + t;
      int c = task >> 4, j = task & 15;
      float4 vb = *(const float4*)(brow + (size_t)c * (HH * WW) + 4 * j);
      float4 vf = *(const float4*)(frow + (size_t)c * (HH * WW) + 4 * j);
      Lb[2 * j][c] = vb.x; Lb[2 * j + 1][c] = vb.z;
      Lf[2 * j][c] = vf.x; Lf[2 * j + 1][c] = vf.z;
    }
    __syncthreads();
    int qw = t >> 3, og = t & 7;
    int col = og * 8;
    int q = qh * 32 + qw;
    float ssq = 0.f;
    s16x8 vbh, vbl, vfh, vfl;
#pragma unroll
    for (int e = 0; e < 8; ++e) {
      float xb = Lb[qw][col + e], xf = Lf[qw][col + e];
      ssq += xb * xb;
      u16 hb = f2bf(xb); u16 lb = f2bf(xb - bf2f(hb));
      u16 hf = f2bf(xf); u16 lf = f2bf(xf - bf2f(hf));
      vbh[e] = (short)hb; vbl[e] = (short)lb; vfh[e] = (short)hf; vfl[e] = (short)lf;
    }
    size_t o = ((size_t)(s * LL) + q) * NC + cg * 64 + col;
    *(s16x8*)(bsT_hi + o) = vbh;
    *(s16x8*)(bsT_lo + o) = vbl;
    *(s16x8*)(fsT_hi + o) = vfh;
    *(s16x8*)(fsT_lo + o) = vfl;
    SS[t] = ssq;
    __syncthreads();
    if (og == 0) {
      float sum = 0.f;
#pragma unroll
      for (int j = 0; j < 8; ++j) sum += SS[qw * 8 + j];
      Qp[cg * (NS * LL) + s * LL + q] = sum;
    }
  } else {
    int b2 = bx - 256;
    int khg = b2 & 3, c = (b2 >> 2) & 127, s = b2 >> 9;
    float (*Lw)[68] = Lb;
    const float* src = b + ((size_t)(s * NC + c) * HH + 16 * khg) * WW;
    float4 v = *(const float4*)(src + (t >> 4) * WW + (t & 15) * 4);
    int rr = t >> 4, qq4 = (t & 15) * 4;
    Lw[rr][qq4] = v.x; Lw[rr][qq4 + 1] = v.y; Lw[rr][qq4 + 2] = v.z; Lw[rr][qq4 + 3] = v.w;
    __syncthreads();
    if (t < 128) {
      int cls = t >> 5, kh_l = (t >> 2) & 7, ko = t & 3;
      int py = cls >> 1, px = cls & 1;
      int y = 2 * kh_l + py;
      s16x8 w;
#pragma unroll
      for (int e = 0; e < 8; ++e) w[e] = (short)f2bf(Lw[y][16 * ko + 2 * e + px]);
      int kh = khg * 8 + kh_l;
      int z = s * 4 + cls;
      *(s16x8*)(Wt + (((size_t)(z * NC + c)) << 10) + kh * 32 + 8 * ko) = w;
    }
  }
}

// ---------------- K2: Gt[q][p] = sum_c fs[c][q]*bs[c][p], split-bf16 MFMA
__global__ __launch_bounds__(256) void gram_mfma(const u16* __restrict__ aT_hi,
                                                 const u16* __restrict__ aT_lo,
                                                 const u16* __restrict__ bT_hi,
                                                 const u16* __restrict__ bT_lo,
                                                 float* __restrict__ G) {
  int wid = blockIdx.x * 4 + (threadIdx.x >> 6);  // 4096 = 4s * 64mt * 16ngg
  int ngg = wid & 15, mt = (wid >> 4) & 63, s = wid >> 10;
  int l = threadIdx.x & 63, lr = l & 15, lg = l >> 4;
  const u16* Ah = aT_hi + ((size_t)(s * LL) + mt * 16 + lr) * NC + lg * 8;
  const u16* Al = aT_lo + ((size_t)(s * LL) + mt * 16 + lr) * NC + lg * 8;
  size_t bbase = ((size_t)(s * LL) + ngg * 64 + lr) * NC + lg * 8;
  f32x4 acc[4] = {};
  s16x8 ah0, al0, bh0[4], bl0[4];
  s16x8 ah1, al1, bh1[4], bl1[4];
  auto LD = [&](int kc, s16x8& ah, s16x8& al, s16x8* bh, s16x8* bl) {
    int o = kc * 32;
    ah = *(const s16x8*)(Ah + o);
    al = *(const s16x8*)(Al + o);
#pragma unroll
    for (int nt = 0; nt < 4; ++nt) {
      bh[nt] = *(const s16x8*)(bT_hi + bbase + nt * 16 * NC + o);
      bl[nt] = *(const s16x8*)(bT_lo + bbase + nt * 16 * NC + o);
    }
  };
  auto ST = [&](s16x8& ah, s16x8& al, s16x8* bh, s16x8* bl) {
#pragma unroll
    for (int nt = 0; nt < 4; ++nt) {
      acc[nt] = __builtin_amdgcn_mfma_f32_16x16x32_bf16(ah, bh[nt], acc[nt], 0, 0, 0);
      acc[nt] = __builtin_amdgcn_mfma_f32_16x16x32_bf16(ah, bl[nt], acc[nt], 0, 0, 0);
      acc[nt] = __builtin_amdgcn_mfma_f32_16x16x32_bf16(al, bh[nt], acc[nt], 0, 0, 0);
    }
  };
  LD(0, ah0, al0, bh0, bl0);
  LD(1, ah1, al1, bh1, bl1);
  ST(ah0, al0, bh0, bl0);
  LD(2, ah0, al0, bh0, bl0);
  ST(ah1, al1, bh1, bl1);
  LD(3, ah1, al1, bh1, bl1);
  ST(ah0, al0, bh0, bl0);
  ST(ah1, al1, bh1, bl1);
  float* Gs = G + ((size_t)s << 20);
  int qrow = mt * 16 + lg * 4;
#pragma unroll
  for (int nt = 0; nt < 4; ++nt) {
    int p0 = ngg * 64 + nt * 16 + lr;
#pragma unroll
    for (int r = 0; r < 4; ++r)
      Gs[(size_t)(qrow + r) * LL + p0] = acc[nt][r];
  }
}

// ---------------- K3: sbuildT + nrm folded; async-staged rows
__global__ __launch_bounds__(256) void sbuildT(const float* __restrict__ Gt,
                                               const float* __restrict__ Qp,
                                               float* __restrict__ St) {
  int g = blockIdx.x;              // 1024 = 4s * 32qh * 8qg
  int qg = g & 7, qh = (g >> 3) & 31, s = g >> 8;
  int qw0 = qg * 4;
  int t = threadIdx.x;
  __shared__ float L[18][1024];    // 72 KB
  __shared__ float Qrow[1024];
  const float* Gs = Gt + ((size_t)s << 20);
  {
    int p4 = t * 4;
    float4 a = *(const float4*)(Qp + s * LL + p4);
    float4 c = *(const float4*)(Qp + NS * LL + s * LL + p4);
    float4 r = make_float4(a.x + c.x, a.y + c.y, a.z + c.z, a.w + c.w);
    *(float4*)&Qrow[p4] = r;
  }
#pragma unroll
  for (int slot = 0; slot < 18; ++slot) {
    int dh = slot / 6 - 1, j = slot % 6;
    int qh2 = qh + dh, qw2 = qw0 - 1 + j;
    bool ok = ((unsigned)qh2 < 32u) && ((unsigned)qw2 < 32u);   // block-uniform
    if (ok)
      gload16(Gs + ((size_t)(qh2 * 32 + qw2) << 10) + t * 4, &L[slot][t * 4]);
    else
      *(float4*)&L[slot][t * 4] = make_float4(0.f, 0.f, 0.f, 0.f);
  }
  __syncthreads();
#pragma unroll
  for (int ii = 0; ii < 4; ++ii) {
    int p = ii * 256 + t;
    int ph = p >> 5, pw = p & 31;
    float sum2 = 1152 * 1e-4f;
#pragma unroll
    for (int dh = -1; dh <= 1; ++dh)
#pragma unroll
      for (int dw = -1; dw <= 1; ++dw) {
        int h = ph + dh, w = pw + dw;
        if ((unsigned)h < 32u && (unsigned)w < 32u) sum2 += Qrow[h * 32 + w];
      }
    float nrp = sqrtf(sum2);
#pragma unroll
    for (int qq = 0; qq < 4; ++qq) {
      float acc = 0.f;
#pragma unroll
      for (int dh = -1; dh <= 1; ++dh)
#pragma unroll
        for (int dw = -1; dw <= 1; ++dw) {
          int ph2 = ph + dh, pw2 = pw + dw;
          if ((unsigned)ph2 < 32u && (unsigned)pw2 < 32u)
            acc += L[(dh + 1) * 6 + qq + dw + 1][p + dh * 32 + dw];
        }
      St[((size_t)s << 20) + ((size_t)(qh * 32 + qw0 + qq) << 10) + p] = acc / nrp;
    }
  }
}

// ---------------- K4: fuse12 + softmax + mask-mean folded; async-staged rows
__global__ __launch_bounds__(256) void fuse12_softmax(const float* __restrict__ St,
                                                      const float* __restrict__ mask,
                                                      float* __restrict__ yiT) {
  int g = blockIdx.x;              // 1024 = 4s * 32qh * 8qg
  int qg = g & 7, qh = (g >> 3) & 31, s = g >> 8;
  int qw0 = qg * 4;
  int q0 = qh * 32 + qw0;
  int t = threadIdx.x;
  int lane = t & 63, wv = t >> 6;
  __shared__ float L[18][1024];    // 72 KB
  __shared__ float Mrow[1024];
  __shared__ float redA[4][4];
  __shared__ float redB[4][4];
  const float* Ss = St + ((size_t)s << 20);
  {
    int p4 = t * 4;
    const float* mrow = mask + s * HH * WW + ((p4 >> 5) * 2) * WW + (p4 & 31) * 2;
    float4 a = *(const float4*)mrow;
    float4 c = *(const float4*)(mrow + 4);
    *(float4*)&Mrow[p4] = make_float4(a.x, a.z, c.x, c.z);
  }
  int base[3];
  base[0] = (qh > 0) ? (q0 - 33) : (992 + qw0 - 2);
  base[1] = q0 - 1;
  base[2] = (qh < 31) ? (q0 + 31) : qw0;
#pragma unroll
  for (int slot = 0; slot < 18; ++slot) {
    int d2 = slot / 6, j = slot % 6;
    int row = base[d2] + j;
    bool ok = (unsigned)row < 1024u;                            // block-uniform
    if (ok)
      gload16(Ss + ((size_t)row << 10) + t * 4, &L[slot][t * 4]);
    else
      *(float4*)&L[slot][t * 4] = make_float4(0.f, 0.f, 0.f, 0.f);
  }
  __syncthreads();
  bool vq0[4], vq2[4];
#pragma unroll
  for (int qq = 0; qq < 4; ++qq) {
    int qw = qw0 + qq;
    vq0[qq] = !(qh == 0 && qw == 0);
    vq2[qq] = !(qh == 31 && qw == 31);
  }
  float v[4][4];
  float mval[4];
  float mxq[4] = {-1e30f, -1e30f, -1e30f, -1e30f};
#pragma unroll
  for (int ii = 0; ii < 4; ++ii) {
    int p = ii * 256 + t;
    int ph = p >> 5, pw = p & 31;
    float msum = 0.f;
#pragma unroll
    for (int dh = -1; dh <= 1; ++dh)
#pragma unroll
      for (int dw = -1; dw <= 1; ++dw) {
        int h = ph + dh, w = pw + dw;
        if ((unsigned)h < 32u && (unsigned)w < 32u) msum += Mrow[h * 32 + w];
      }
    mval[ii] = msum * (1.f / 9.f);
    int rp[3]; bool vp[3];
    if (ph > 0)      { rp[0] = p - 32;        vp[0] = true; }
    else if (pw > 0) { rp[0] = 992 + pw - 1;  vp[0] = true; }
    else             { rp[0] = 0;             vp[0] = false; }
    rp[1] = p; vp[1] = true;
    if (ph < 31)      { rp[2] = p + 32;   vp[2] = true; }
    else if (pw < 31) { rp[2] = pw + 1;   vp[2] = true; }
    else              { rp[2] = 0;        vp[2] = false; }
#pragma unroll
    for (int qq = 0; qq < 4; ++qq) {
      float acc = 0.f;
#pragma unroll
      for (int d2 = 0; d2 < 3; ++d2) {
        bool vq = (d2 == 0) ? vq0[qq] : ((d2 == 2) ? vq2[qq] : true);
        if (vq && vp[d2]) {
#pragma unroll
          for (int d1 = -1; d1 <= 1; ++d1) {
            int cc = rp[d2] + d1;
            if ((unsigned)cc < 1024u)
              acc += L[d2 * 6 + qq + d1 + 1][cc];
          }
        }
      }
      float val = acc * mval[ii] * 10.f;
      v[ii][qq] = val;
      mxq[qq] = fmaxf(mxq[qq], val);
    }
  }
#pragma unroll
  for (int qq = 0; qq < 4; ++qq) {
    float m = mxq[qq];
#pragma unroll
    for (int o = 32; o; o >>= 1) m = fmaxf(m, __shfl_xor(m, o));
    if (lane == 0) redA[wv][qq] = m;
  }
  __syncthreads();
  float fm[4], sq[4] = {0.f, 0.f, 0.f, 0.f};
#pragma unroll
  for (int qq = 0; qq < 4; ++qq)
    fm[qq] = fmaxf(fmaxf(redA[0][qq], redA[1][qq]), fmaxf(redA[2][qq], redA[3][qq]));
#pragma unroll
  for (int ii = 0; ii < 4; ++ii)
#pragma unroll
    for (int qq = 0; qq < 4; ++qq) {
      v[ii][qq] = __expf(v[ii][qq] - fm[qq]);
      sq[qq] += v[ii][qq];
    }
#pragma unroll
  for (int qq = 0; qq < 4; ++qq) {
    float sm = sq[qq];
#pragma unroll
    for (int o = 32; o; o >>= 1) sm += __shfl_xor(sm, o);
    if (lane == 0) redB[wv][qq] = sm;
  }
  __syncthreads();
  float inv[4];
#pragma unroll
  for (int qq = 0; qq < 4; ++qq)
    inv[qq] = 1.f / ((redB[0][qq] + redB[1][qq]) + (redB[2][qq] + redB[3][qq]));
#pragma unroll
  for (int qq = 0; qq < 4; ++qq) {
    float* yo = yiT + ((size_t)s << 20) + ((size_t)(q0 + qq) << 10);
#pragma unroll
    for (int ii = 0; ii < 4; ++ii) {
      int p = ii * 256 + t;
      yo[p] = v[ii][qq] * inv[qq] * mval[ii];
    }
  }
}

// ---------------- K5: build P (4-tap diagonal sums of yiT) as bf16; async-staged
__global__ __launch_bounds__(256) void build_p(const float* __restrict__ yiT,
                                               u16* __restrict__ Pb) {
  int bx = blockIdx.x;               // 1024 = 4s * 32ih * 8jg
  int jg = bx & 7, ih = (bx >> 3) & 31, s = bx >> 8;
  int jw0 = jg * 4;
  const float* Y = yiT + ((size_t)s << 20);
  __shared__ float R[18][1024];
  int t = threadIdx.x;
#pragma unroll
  for (int r = 0; r < 18; ++r) {
    int di = r / 6, jj = r % 6;
    int ihh = ih + di - 1, jww = jw0 + jj - 1;
    bool vld = ((unsigned)ihh < 32u) && ((unsigned)jww < 32u);  // block-uniform
    if (vld)
      gload16(Y + ((size_t)(ihh * 32 + jww) << 10) + t * 4, &R[r][t * 4]);
    else
      *(float4*)&R[r][t * 4] = make_float4(0.f, 0.f, 0.f, 0.f);
  }
  __syncthreads();
  int nl = t >> 6, lane = t & 63;
  int n = ih * 32 + jw0 + nl;
#pragma unroll
  for (int kq = 0; kq < 4; ++kq) {
    int k0 = (kq * 64 + lane) * 4;
    int kh = k0 >> 5;
#pragma unroll
    for (int cls = 0; cls < 4; ++cls) {
      int py = cls >> 1, px = cls & 1;
      int sy = py ? 1 : -1, sx = px ? 1 : -1;
      const float* RA = R[6 + nl + 1];
      const float* RB = R[(1 + sy) * 6 + nl + 1];
      const float* RC = R[6 + nl + 1 + sx];
      const float* RD = R[(1 + sy) * 6 + nl + 1 + sx];
      bool mB = (unsigned)(kh + sy) < 32u;
      int ob = 32 * sy;
      u16x4 pk;
#pragma unroll
      for (int e = 0; e < 4; ++e) {
        int k = k0 + e, kw = k & 31;
        bool mC = (unsigned)(kw + sx) < 32u;
        float v = RA[k];
        if (mB) v += RB[k + ob];
        if (mC) v += RC[k + sx];
        if (mB && mC) v += RD[k + ob + sx];
        pk[e] = f2bf(v);
      }
      int zz = s * 4 + cls;
      *(u16x4*)(Pb + (((size_t)(zz * LL + n)) << 10) + k0) = pk;
    }
  }
}

// ---------------- K6: deconv GEMM v5 — m97-style global_load_lds double-buffer
__global__ __launch_bounds__(256, 1) void deconv_gemm(const u16* __restrict__ Pb,
                                                      const u16* __restrict__ Wt,
                                                      float* __restrict__ out) {
  int bx = blockIdx.x;
  int nb = bx & 7, cb = (bx >> 3) & 1, z = bx >> 4;
  int s = z >> 2, cls = z & 3, py = cls >> 1, px = cls & 1;
  int t = threadIdx.x, w = t >> 6, l = t & 63, lr = l & 15, lg = l >> 4;
  int wc = w >> 1, wn = w & 1;
  int c0 = cb * 64, n0 = nb * 128;
  __shared__ __align__(16) u16 SA[2][64 * 64];
  __shared__ __align__(16) u16 SB[2][128 * 64];
  const u16* Ag = Wt + ((size_t)(z * NC + c0)) * LL;
  const u16* Bg = Pb + ((size_t)(z * LL + n0)) * LL;
  int rA  = l >> 3;
  int swz = ((l & 7) ^ (rA & 7)) * 8;

  auto STAGE = [&](int buf, int k0) {
#pragma unroll
    for (int j = 0; j < 6; ++j) {
      int ci = w * 6 + j;
      if (ci < 8) {
        const u16* src = Ag + ((size_t)(ci * 8 + rA)) * LL + k0 + swz;
        gload16(src, &SA[buf][ci * 512]);
      } else {
        int cj = ci - 8;
        const u16* src = Bg + ((size_t)(cj * 8 + rA)) * LL + k0 + swz;
        gload16(src, &SB[buf][cj * 512]);
      }
    }
  };
#define ARD(r, o) (*(const s16x8*)((const char*)&SA[buf][0] + (r) * 128 + (((o) * 16) ^ (((r) & 7) << 4))))
#define BRD(r, o) (*(const s16x8*)((const char*)&SB[buf][0] + (r) * 128 + (((o) * 16) ^ (((r) & 7) << 4))))

  f32x4 acc[2][4] = {};
  int buf = 0;
  STAGE(0, 0);
#pragma unroll 1
  for (int it = 0; it < 16; ++it) {
    __syncthreads();
    if (it < 15) STAGE(buf ^ 1, (it + 1) * 64);
#pragma unroll
    for (int ks = 0; ks < 2; ++ks) {
      int o = ks * 4 + lg;
      s16x8 a0 = ARD(wc * 32 + lr, o);
      s16x8 a1 = ARD(wc * 32 + 16 + lr, o);
      s16x8 b0 = BRD(wn * 64 + lr, o);
      s16x8 b1 = BRD(wn * 64 + 16 + lr, o);
      s16x8 b2 = BRD(wn * 64 + 32 + lr, o);
      s16x8 b3 = BRD(wn * 64 + 48 + lr, o);
      acc[0][0] = __builtin_amdgcn_mfma_f32_16x16x32_bf16(a0, b0, acc[0][0], 0, 0, 0);
      acc[0][1] = __builtin_amdgcn_mfma_f32_16x16x32_bf16(a0, b1, acc[0][1], 0, 0, 0);
      acc[0][2] = __builtin_amdgcn_mfma_f32_16x16x32_bf16(a0, b2, acc[0][2], 0, 0, 0);
      acc[0][3] = __builtin_amdgcn_mfma_f32_16x16x32_bf16(a0, b3, acc[0][3], 0, 0, 0);
      acc[1][0] = __builtin_amdgcn_mfma_f32_16x16x32_bf16(a1, b0, acc[1][0], 0, 0, 0);
      acc[1][1] = __builtin_amdgcn_mfma_f32_16x16x32_bf16(a1, b1, acc[1][1], 0, 0, 0);
      acc[1][2] = __builtin_amdgcn_mfma_f32_16x16x32_bf16(a1, b2, acc[1][2], 0, 0, 0);
      acc[1][3] = __builtin_amdgcn_mfma_f32_16x16x32_bf16(a1, b3, acc[1][3], 0, 0, 0);
    }
    __syncthreads();
    buf ^= 1;
  }
  float* os = out + (size_t)s * NC * HH * WW;
#pragma unroll
  for (int mt = 0; mt < 2; ++mt) {
    int cc = c0 + wc * 32 + mt * 16 + lg * 4;
#pragma unroll
    for (int nt = 0; nt < 4; ++nt) {
      int nn = n0 + wn * 64 + nt * 16 + lr;
      size_t ob = (size_t)(2 * (nn >> 5) + py) * WW + 2 * (nn & 31) + px;
#pragma unroll
      for (int r = 0; r < 4; ++r)
        os[(size_t)(cc + r) * (HH * WW) + ob] = acc[mt][nt][r] * 0.25f;
    }
  }
#undef ARD
#undef BRD
}

extern "C" void kernel_launch(void* const* d_in, const int* in_sizes, int n_in,
                              void* d_out, int out_size, void* d_ws, size_t ws_size,
                              hipStream_t stream) {
  const float* f    = (const float*)d_in[0];
  const float* b    = (const float*)d_in[1];
  const float* mask = (const float*)d_in[2];
  float* out  = (float*)d_out;

  float* buf0 = (float*)d_ws;              // Gt -> yiT
  float* buf1 = buf0 + 4194304;            // St
  u16* bsT_hi = (u16*)(buf1 + 4194304);
  u16* bsT_lo = bsT_hi + 524288;
  u16* fsT_hi = bsT_lo + 524288;
  u16* fsT_lo = fsT_hi + 524288;
  u16* Wt     = fsT_lo + 524288;           // 2,097,152 u16
  float* Qp   = (float*)(Wt + 2097152);    // 8,192
  u16* Pb     = (u16*)(Qp + 8192);         // 16,777,216 u16 (32 MB)

  hipLaunchKernelGGL(prep_all, dim3(2304), dim3(256), 0, stream, f, b, bsT_hi, bsT_lo, fsT_hi, fsT_lo, Qp, Wt);
  hipLaunchKernelGGL(gram_mfma, dim3(1024), dim3(256), 0, stream, fsT_hi, fsT_lo, bsT_hi, bsT_lo, buf0);
  hipLaunchKernelGGL(sbuildT, dim3(1024), dim3(256), 0, stream, buf0, Qp, buf1);
  hipLaunchKernelGGL(fuse12_softmax, dim3(1024), dim3(256), 0, stream, buf1, mask, buf0);
  hipLaunchKernelGGL(build_p, dim3(1024), dim3(256), 0, stream, buf0, Pb);
  hipLaunchKernelGGL(deconv_gemm, dim3(256), dim3(256), 0, stream, Pb, Wt, out);
}

// Round 13
// 112.960 us; speedup vs baseline: 1.1986x; 1.0577x over previous
//
#include <hip/hip_runtime.h>
#include <math.h>

#define NS 4
#define NC 128
#define HH 64
#define WW 64
#define LL 1024   // 32*32

typedef unsigned short u16;
typedef u16 u16x4 __attribute__((ext_vector_type(4)));
typedef short s16x8 __attribute__((ext_vector_type(8)));
typedef float f32x4 __attribute__((ext_vector_type(4)));

__device__ __forceinline__ u16 f2bf(float x) {
  unsigned u = __float_as_uint(x);
  return (u16)((u + 0x7FFFu + ((u >> 16) & 1u)) >> 16);
}
__device__ __forceinline__ float bf2f(u16 h) {
  return __uint_as_float(((unsigned)h) << 16);
}
__device__ __forceinline__ void gload16(const void* g, void* l) {
  __builtin_amdgcn_global_load_lds((const __attribute__((address_space(1))) void*)g,
                                   (__attribute__((address_space(3))) void*)l, 16, 0, 0);
}

// ---------------- K1: prep (256 blocks) + prep_wt (2048 blocks) in one launch
__global__ __launch_bounds__(256) void prep_all(const float* __restrict__ f,
                                                const float* __restrict__ b,
                                                u16* __restrict__ bsT_hi, u16* __restrict__ bsT_lo,
                                                u16* __restrict__ fsT_hi, u16* __restrict__ fsT_lo,
                                                float* __restrict__ Qp,
                                                u16* __restrict__ Wt) {
  int bx = blockIdx.x;
  int t = threadIdx.x;
  __shared__ float Lb[32][68];
  __shared__ float Lf[32][68];
  __shared__ float SS[256];
  if (bx < 256) {
    int cg = bx & 1, qh = (bx >> 1) & 31, s = bx >> 6;
    const float* brow = b + ((size_t)(s * NC + cg * 64) * HH + 2 * qh) * WW;
    const float* frow = f + ((size_t)(s * NC + cg * 64) * HH + 2 * qh) * WW;
#pragma unroll
    for (int i = 0; i < 4; ++i) {
      int task = i * 256 + t;
      int c = task >> 4, j = task & 15;
      float4 vb = *(const float4*)(brow + (size_t)c * (HH * WW) + 4 * j);
      float4 vf = *(const float4*)(frow + (size_t)c * (HH * WW) + 4 * j);
      Lb[2 * j][c] = vb.x; Lb[2 * j + 1][c] = vb.z;
      Lf[2 * j][c] = vf.x; Lf[2 * j + 1][c] = vf.z;
    }
    __syncthreads();
    int qw = t >> 3, og = t & 7;
    int col = og * 8;
    int q = qh * 32 + qw;
    float ssq = 0.f;
    s16x8 vbh, vbl, vfh, vfl;
#pragma unroll
    for (int e = 0; e < 8; ++e) {
      float xb = Lb[qw][col + e], xf = Lf[qw][col + e];
      ssq += xb * xb;
      u16 hb = f2bf(xb); u16 lb = f2bf(xb - bf2f(hb));
      u16 hf = f2bf(xf); u16 lf = f2bf(xf - bf2f(hf));
      vbh[e] = (short)hb; vbl[e] = (short)lb; vfh[e] = (short)hf; vfl[e] = (short)lf;
    }
    size_t o = ((size_t)(s * LL) + q) * NC + cg * 64 + col;
    *(s16x8*)(bsT_hi + o) = vbh;
    *(s16x8*)(bsT_lo + o) = vbl;
    *(s16x8*)(fsT_hi + o) = vfh;
    *(s16x8*)(fsT_lo + o) = vfl;
    SS[t] = ssq;
    __syncthreads();
    if (og == 0) {
      float sum = 0.f;
#pragma unroll
      for (int j = 0; j < 8; ++j) sum += SS[qw * 8 + j];
      Qp[cg * (NS * LL) + s * LL + q] = sum;
    }
  } else {
    int b2 = bx - 256;
    int khg = b2 & 3, c = (b2 >> 2) & 127, s = b2 >> 9;
    float (*Lw)[68] = Lb;
    const float* src = b + ((size_t)(s * NC + c) * HH + 16 * khg) * WW;
    float4 v = *(const float4*)(src + (t >> 4) * WW + (t & 15) * 4);
    int rr = t >> 4, qq4 = (t & 15) * 4;
    Lw[rr][qq4] = v.x; Lw[rr][qq4 + 1] = v.y; Lw[rr][qq4 + 2] = v.z; Lw[rr][qq4 + 3] = v.w;
    __syncthreads();
    if (t < 128) {
      int cls = t >> 5, kh_l = (t >> 2) & 7, ko = t & 3;
      int py = cls >> 1, px = cls & 1;
      int y = 2 * kh_l + py;
      s16x8 w;
#pragma unroll
      for (int e = 0; e < 8; ++e) w[e] = (short)f2bf(Lw[y][16 * ko + 2 * e + px]);
      int kh = khg * 8 + kh_l;
      int z = s * 4 + cls;
      *(s16x8*)(Wt + (((size_t)(z * NC + c)) << 10) + kh * 32 + 8 * ko) = w;
    }
  }
}

// ---------------- K2: gram v2 — Gt[q][p] = sum_c fs[c][q]*bs[c][p].
// Wave = 32 q-rows x 64 p-cols (2 A-tiles x 4 B-tiles): B-fragments reused
// by both A-tiles -> B L2-traffic halved vs v1. 2048 waves = 512 blocks.
__global__ __launch_bounds__(256) void gram_mfma(const u16* __restrict__ aT_hi,
                                                 const u16* __restrict__ aT_lo,
                                                 const u16* __restrict__ bT_hi,
                                                 const u16* __restrict__ bT_lo,
                                                 float* __restrict__ G) {
  int wid = blockIdx.x * 4 + (threadIdx.x >> 6);  // 2048 = 4s * 32mt2 * 16ngg
  int ngg = wid & 15, mt2 = (wid >> 4) & 31, s = wid >> 9;
  int l = threadIdx.x & 63, lr = l & 15, lg = l >> 4;
  size_t abase = ((size_t)(s * LL) + mt2 * 32 + lr) * NC + lg * 8;
  size_t bbase = ((size_t)(s * LL) + ngg * 64 + lr) * NC + lg * 8;
  f32x4 acc[2][4] = {};
#pragma unroll
  for (int kc = 0; kc < 4; ++kc) {
    int o = kc * 32;
    s16x8 ah0 = *(const s16x8*)(aT_hi + abase + o);
    s16x8 al0 = *(const s16x8*)(aT_lo + abase + o);
    s16x8 ah1 = *(const s16x8*)(aT_hi + abase + (size_t)16 * NC + o);
    s16x8 al1 = *(const s16x8*)(aT_lo + abase + (size_t)16 * NC + o);
#pragma unroll
    for (int nt = 0; nt < 4; ++nt) {
      s16x8 bh = *(const s16x8*)(bT_hi + bbase + (size_t)(nt * 16) * NC + o);
      s16x8 bl = *(const s16x8*)(bT_lo + bbase + (size_t)(nt * 16) * NC + o);
      acc[0][nt] = __builtin_amdgcn_mfma_f32_16x16x32_bf16(ah0, bh, acc[0][nt], 0, 0, 0);
      acc[0][nt] = __builtin_amdgcn_mfma_f32_16x16x32_bf16(ah0, bl, acc[0][nt], 0, 0, 0);
      acc[0][nt] = __builtin_amdgcn_mfma_f32_16x16x32_bf16(al0, bh, acc[0][nt], 0, 0, 0);
      acc[1][nt] = __builtin_amdgcn_mfma_f32_16x16x32_bf16(ah1, bh, acc[1][nt], 0, 0, 0);
      acc[1][nt] = __builtin_amdgcn_mfma_f32_16x16x32_bf16(ah1, bl, acc[1][nt], 0, 0, 0);
      acc[1][nt] = __builtin_amdgcn_mfma_f32_16x16x32_bf16(al1, bh, acc[1][nt], 0, 0, 0);
    }
  }
  float* Gs = G + ((size_t)s << 20);
#pragma unroll
  for (int mtl = 0; mtl < 2; ++mtl) {
    int qrow = mt2 * 32 + mtl * 16 + lg * 4;
#pragma unroll
    for (int nt = 0; nt < 4; ++nt) {
      int p0 = ngg * 64 + nt * 16 + lr;
#pragma unroll
      for (int r = 0; r < 4; ++r)
        Gs[(size_t)(qrow + r) * LL + p0] = acc[mtl][nt][r];
    }
  }
}

// ---------------- K3: sbuildT + nrm folded; async-staged rows
__global__ __launch_bounds__(256) void sbuildT(const float* __restrict__ Gt,
                                               const float* __restrict__ Qp,
                                               float* __restrict__ St) {
  int g = blockIdx.x;              // 1024 = 4s * 32qh * 8qg
  int qg = g & 7, qh = (g >> 3) & 31, s = g >> 8;
  int qw0 = qg * 4;
  int t = threadIdx.x;
  __shared__ float L[18][1024];    // 72 KB
  __shared__ float Qrow[1024];
  const float* Gs = Gt + ((size_t)s << 20);
  {
    int p4 = t * 4;
    float4 a = *(const float4*)(Qp + s * LL + p4);
    float4 c = *(const float4*)(Qp + NS * LL + s * LL + p4);
    float4 r = make_float4(a.x + c.x, a.y + c.y, a.z + c.z, a.w + c.w);
    *(float4*)&Qrow[p4] = r;
  }
#pragma unroll
  for (int slot = 0; slot < 18; ++slot) {
    int dh = slot / 6 - 1, j = slot % 6;
    int qh2 = qh + dh, qw2 = qw0 - 1 + j;
    bool ok = ((unsigned)qh2 < 32u) && ((unsigned)qw2 < 32u);   // block-uniform
    if (ok)
      gload16(Gs + ((size_t)(qh2 * 32 + qw2) << 10) + t * 4, &L[slot][t * 4]);
    else
      *(float4*)&L[slot][t * 4] = make_float4(0.f, 0.f, 0.f, 0.f);
  }
  __syncthreads();
#pragma unroll
  for (int ii = 0; ii < 4; ++ii) {
    int p = ii * 256 + t;
    int ph = p >> 5, pw = p & 31;
    float sum2 = 1152 * 1e-4f;
#pragma unroll
    for (int dh = -1; dh <= 1; ++dh)
#pragma unroll
      for (int dw = -1; dw <= 1; ++dw) {
        int h = ph + dh, w = pw + dw;
        if ((unsigned)h < 32u && (unsigned)w < 32u) sum2 += Qrow[h * 32 + w];
      }
    float nrp = sqrtf(sum2);
#pragma unroll
    for (int qq = 0; qq < 4; ++qq) {
      float acc = 0.f;
#pragma unroll
      for (int dh = -1; dh <= 1; ++dh)
#pragma unroll
        for (int dw = -1; dw <= 1; ++dw) {
          int ph2 = ph + dh, pw2 = pw + dw;
          if ((unsigned)ph2 < 32u && (unsigned)pw2 < 32u)
            acc += L[(dh + 1) * 6 + qq + dw + 1][p + dh * 32 + dw];
        }
      St[((size_t)s << 20) + ((size_t)(qh * 32 + qw0 + qq) << 10) + p] = acc / nrp;
    }
  }
}

// ---------------- K4: fuse12 + softmax + mask-mean folded; async-staged rows
__global__ __launch_bounds__(256) void fuse12_softmax(const float* __restrict__ St,
                                                      const float* __restrict__ mask,
                                                      float* __restrict__ yiT) {
  int g = blockIdx.x;              // 1024 = 4s * 32qh * 8qg
  int qg = g & 7, qh = (g >> 3) & 31, s = g >> 8;
  int qw0 = qg * 4;
  int q0 = qh * 32 + qw0;
  int t = threadIdx.x;
  int lane = t & 63, wv = t >> 6;
  __shared__ float L[18][1024];    // 72 KB
  __shared__ float Mrow[1024];
  __shared__ float redA[4][4];
  __shared__ float redB[4][4];
  const float* Ss = St + ((size_t)s << 20);
  {
    int p4 = t * 4;
    const float* mrow = mask + s * HH * WW + ((p4 >> 5) * 2) * WW + (p4 & 31) * 2;
    float4 a = *(const float4*)mrow;
    float4 c = *(const float4*)(mrow + 4);
    *(float4*)&Mrow[p4] = make_float4(a.x, a.z, c.x, c.z);
  }
  int base[3];
  base[0] = (qh > 0) ? (q0 - 33) : (992 + qw0 - 2);
  base[1] = q0 - 1;
  base[2] = (qh < 31) ? (q0 + 31) : qw0;
#pragma unroll
  for (int slot = 0; slot < 18; ++slot) {
    int d2 = slot / 6, j = slot % 6;
    int row = base[d2] + j;
    bool ok = (unsigned)row < 1024u;                            // block-uniform
    if (ok)
      gload16(Ss + ((size_t)row << 10) + t * 4, &L[slot][t * 4]);
    else
      *(float4*)&L[slot][t * 4] = make_float4(0.f, 0.f, 0.f, 0.f);
  }
  __syncthreads();
  bool vq0[4], vq2[4];
#pragma unroll
  for (int qq = 0; qq < 4; ++qq) {
    int qw = qw0 + qq;
    vq0[qq] = !(qh == 0 && qw == 0);
    vq2[qq] = !(qh == 31 && qw == 31);
  }
  float v[4][4];
  float mval[4];
  float mxq[4] = {-1e30f, -1e30f, -1e30f, -1e30f};
#pragma unroll
  for (int ii = 0; ii < 4; ++ii) {
    int p = ii * 256 + t;
    int ph = p >> 5, pw = p & 31;
    float msum = 0.f;
#pragma unroll
    for (int dh = -1; dh <= 1; ++dh)
#pragma unroll
      for (int dw = -1; dw <= 1; ++dw) {
        int h = ph + dh, w = pw + dw;
        if ((unsigned)h < 32u && (unsigned)w < 32u) msum += Mrow[h * 32 + w];
      }
    mval[ii] = msum * (1.f / 9.f);
    int rp[3]; bool vp[3];
    if (ph > 0)      { rp[0] = p - 32;        vp[0] = true; }
    else if (pw > 0) { rp[0] = 992 + pw - 1;  vp[0] = true; }
    else             { rp[0] = 0;             vp[0] = false; }
    rp[1] = p; vp[1] = true;
    if (ph < 31)      { rp[2] = p + 32;   vp[2] = true; }
    else if (pw < 31) { rp[2] = pw + 1;   vp[2] = true; }
    else              { rp[2] = 0;        vp[2] = false; }
#pragma unroll
    for (int qq = 0; qq < 4; ++qq) {
      float acc = 0.f;
#pragma unroll
      for (int d2 = 0; d2 < 3; ++d2) {
        bool vq = (d2 == 0) ? vq0[qq] : ((d2 == 2) ? vq2[qq] : true);
        if (vq && vp[d2]) {
#pragma unroll
          for (int d1 = -1; d1 <= 1; ++d1) {
            int cc = rp[d2] + d1;
            if ((unsigned)cc < 1024u)
              acc += L[d2 * 6 + qq + d1 + 1][cc];
          }
        }
      }
      float val = acc * mval[ii] * 10.f;
      v[ii][qq] = val;
      mxq[qq] = fmaxf(mxq[qq], val);
    }
  }
#pragma unroll
  for (int qq = 0; qq < 4; ++qq) {
    float m = mxq[qq];
#pragma unroll
    for (int o = 32; o; o >>= 1) m = fmaxf(m, __shfl_xor(m, o));
    if (lane == 0) redA[wv][qq] = m;
  }
  __syncthreads();
  float fm[4], sq[4] = {0.f, 0.f, 0.f, 0.f};
#pragma unroll
  for (int qq = 0; qq < 4; ++qq)
    fm[qq] = fmaxf(fmaxf(redA[0][qq], redA[1][qq]), fmaxf(redA[2][qq], redA[3][qq]));
#pragma unroll
  for (int ii = 0; ii < 4; ++ii)
#pragma unroll
    for (int qq = 0; qq < 4; ++qq) {
      v[ii][qq] = __expf(v[ii][qq] - fm[qq]);
      sq[qq] += v[ii][qq];
    }
#pragma unroll
  for (int qq = 0; qq < 4; ++qq) {
    float sm = sq[qq];
#pragma unroll
    for (int o = 32; o; o >>= 1) sm += __shfl_xor(sm, o);
    if (lane == 0) redB[wv][qq] = sm;
  }
  __syncthreads();
  float inv[4];
#pragma unroll
  for (int qq = 0; qq < 4; ++qq)
    inv[qq] = 1.f / ((redB[0][qq] + redB[1][qq]) + (redB[2][qq] + redB[3][qq]));
#pragma unroll
  for (int qq = 0; qq < 4; ++qq) {
    float* yo = yiT + ((size_t)s << 20) + ((size_t)(q0 + qq) << 10);
#pragma unroll
    for (int ii = 0; ii < 4; ++ii) {
      int p = ii * 256 + t;
      yo[p] = v[ii][qq] * inv[qq] * mval[ii];
    }
  }
}

// ---------------- K5: build P (4-tap diagonal sums of yiT) as bf16; async-staged
__global__ __launch_bounds__(256) void build_p(const float* __restrict__ yiT,
                                               u16* __restrict__ Pb) {
  int bx = blockIdx.x;               // 1024 = 4s * 32ih * 8jg
  int jg = bx & 7, ih = (bx >> 3) & 31, s = bx >> 8;
  int jw0 = jg * 4;
  const float* Y = yiT + ((size_t)s << 20);
  __shared__ float R[18][1024];
  int t = threadIdx.x;
#pragma unroll
  for (int r = 0; r < 18; ++r) {
    int di = r / 6, jj = r % 6;
    int ihh = ih + di - 1, jww = jw0 + jj - 1;
    bool vld = ((unsigned)ihh < 32u) && ((unsigned)jww < 32u);  // block-uniform
    if (vld)
      gload16(Y + ((size_t)(ihh * 32 + jww) << 10) + t * 4, &R[r][t * 4]);
    else
      *(float4*)&R[r][t * 4] = make_float4(0.f, 0.f, 0.f, 0.f);
  }
  __syncthreads();
  int nl = t >> 6, lane = t & 63;
  int n = ih * 32 + jw0 + nl;
#pragma unroll
  for (int kq = 0; kq < 4; ++kq) {
    int k0 = (kq * 64 + lane) * 4;
    int kh = k0 >> 5;
#pragma unroll
    for (int cls = 0; cls < 4; ++cls) {
      int py = cls >> 1, px = cls & 1;
      int sy = py ? 1 : -1, sx = px ? 1 : -1;
      const float* RA = R[6 + nl + 1];
      const float* RB = R[(1 + sy) * 6 + nl + 1];
      const float* RC = R[6 + nl + 1 + sx];
      const float* RD = R[(1 + sy) * 6 + nl + 1 + sx];
      bool mB = (unsigned)(kh + sy) < 32u;
      int ob = 32 * sy;
      u16x4 pk;
#pragma unroll
      for (int e = 0; e < 4; ++e) {
        int k = k0 + e, kw = k & 31;
        bool mC = (unsigned)(kw + sx) < 32u;
        float v = RA[k];
        if (mB) v += RB[k + ob];
        if (mC) v += RC[k + sx];
        if (mB && mC) v += RD[k + ob + sx];
        pk[e] = f2bf(v);
      }
      int zz = s * 4 + cls;
      *(u16x4*)(Pb + (((size_t)(zz * LL + n)) << 10) + k0) = pk;
    }
  }
}

// ---------------- K6: deconv GEMM v5 — m97-style global_load_lds double-buffer
__global__ __launch_bounds__(256, 1) void deconv_gemm(const u16* __restrict__ Pb,
                                                      const u16* __restrict__ Wt,
                                                      float* __restrict__ out) {
  int bx = blockIdx.x;
  int nb = bx & 7, cb = (bx >> 3) & 1, z = bx >> 4;
  int s = z >> 2, cls = z & 3, py = cls >> 1, px = cls & 1;
  int t = threadIdx.x, w = t >> 6, l = t & 63, lr = l & 15, lg = l >> 4;
  int wc = w >> 1, wn = w & 1;
  int c0 = cb * 64, n0 = nb * 128;
  __shared__ __align__(16) u16 SA[2][64 * 64];
  __shared__ __align__(16) u16 SB[2][128 * 64];
  const u16* Ag = Wt + ((size_t)(z * NC + c0)) * LL;
  const u16* Bg = Pb + ((size_t)(z * LL + n0)) * LL;
  int rA  = l >> 3;
  int swz = ((l & 7) ^ (rA & 7)) * 8;

  auto STAGE = [&](int buf, int k0) {
#pragma unroll
    for (int j = 0; j < 6; ++j) {
      int ci = w * 6 + j;
      if (ci < 8) {
        const u16* src = Ag + ((size_t)(ci * 8 + rA)) * LL + k0 + swz;
        gload16(src, &SA[buf][ci * 512]);
      } else {
        int cj = ci - 8;
        const u16* src = Bg + ((size_t)(cj * 8 + rA)) * LL + k0 + swz;
        gload16(src, &SB[buf][cj * 512]);
      }
    }
  };
#define ARD(r, o) (*(const s16x8*)((const char*)&SA[buf][0] + (r) * 128 + (((o) * 16) ^ (((r) & 7) << 4))))
#define BRD(r, o) (*(const s16x8*)((const char*)&SB[buf][0] + (r) * 128 + (((o) * 16) ^ (((r) & 7) << 4))))

  f32x4 acc[2][4] = {};
  int buf = 0;
  STAGE(0, 0);
#pragma unroll 1
  for (int it = 0; it < 16; ++it) {
    __syncthreads();
    if (it < 15) STAGE(buf ^ 1, (it + 1) * 64);
#pragma unroll
    for (int ks = 0; ks < 2; ++ks) {
      int o = ks * 4 + lg;
      s16x8 a0 = ARD(wc * 32 + lr, o);
      s16x8 a1 = ARD(wc * 32 + 16 + lr, o);
      s16x8 b0 = BRD(wn * 64 + lr, o);
      s16x8 b1 = BRD(wn * 64 + 16 + lr, o);
      s16x8 b2 = BRD(wn * 64 + 32 + lr, o);
      s16x8 b3 = BRD(wn * 64 + 48 + lr, o);
      acc[0][0] = __builtin_amdgcn_mfma_f32_16x16x32_bf16(a0, b0, acc[0][0], 0, 0, 0);
      acc[0][1] = __builtin_amdgcn_mfma_f32_16x16x32_bf16(a0, b1, acc[0][1], 0, 0, 0);
      acc[0][2] = __builtin_amdgcn_mfma_f32_16x16x32_bf16(a0, b2, acc[0][2], 0, 0, 0);
      acc[0][3] = __builtin_amdgcn_mfma_f32_16x16x32_bf16(a0, b3, acc[0][3], 0, 0, 0);
      acc[1][0] = __builtin_amdgcn_mfma_f32_16x16x32_bf16(a1, b0, acc[1][0], 0, 0, 0);
      acc[1][1] = __builtin_amdgcn_mfma_f32_16x16x32_bf16(a1, b1, acc[1][1], 0, 0, 0);
      acc[1][2] = __builtin_amdgcn_mfma_f32_16x16x32_bf16(a1, b2, acc[1][2], 0, 0, 0);
      acc[1][3] = __builtin_amdgcn_mfma_f32_16x16x32_bf16(a1, b3, acc[1][3], 0, 0, 0);
    }
    __syncthreads();
    buf ^= 1;
  }
  float* os = out + (size_t)s * NC * HH * WW;
#pragma unroll
  for (int mt = 0; mt < 2; ++mt) {
    int cc = c0 + wc * 32 + mt * 16 + lg * 4;
#pragma unroll
    for (int nt = 0; nt < 4; ++nt) {
      int nn = n0 + wn * 64 + nt * 16 + lr;
      size_t ob = (size_t)(2 * (nn >> 5) + py) * WW + 2 * (nn & 31) + px;
#pragma unroll
      for (int r = 0; r < 4; ++r)
        os[(size_t)(cc + r) * (HH * WW) + ob] = acc[mt][nt][r] * 0.25f;
    }
  }
#undef ARD
#undef BRD
}

extern "C" void kernel_launch(void* const* d_in, const int* in_sizes, int n_in,
                              void* d_out, int out_size, void* d_ws, size_t ws_size,
                              hipStream_t stream) {
  const float* f    = (const float*)d_in[0];
  const float* b    = (const float*)d_in[1];
  const float* mask = (const float*)d_in[2];
  float* out  = (float*)d_out;

  float* buf0 = (float*)d_ws;              // Gt -> yiT
  float* buf1 = buf0 + 4194304;            // St
  u16* bsT_hi = (u16*)(buf1 + 4194304);
  u16* bsT_lo = bsT_hi + 524288;
  u16* fsT_hi = bsT_lo + 524288;
  u16* fsT_lo = fsT_hi + 524288;
  u16* Wt     = fsT_lo + 524288;           // 2,097,152 u16
  float* Qp   = (float*)(Wt + 2097152);    // 8,192
  u16* Pb     = (u16*)(Qp + 8192);         // 16,777,216 u16 (32 MB)

  hipLaunchKernelGGL(prep_all, dim3(2304), dim3(256), 0, stream, f, b, bsT_hi, bsT_lo, fsT_hi, fsT_lo, Qp, Wt);
  hipLaunchKernelGGL(gram_mfma, dim3(512), dim3(256), 0, stream, fsT_hi, fsT_lo, bsT_hi, bsT_lo, buf0);
  hipLaunchKernelGGL(sbuildT, dim3(1024), dim3(256), 0, stream, buf0, Qp, buf1);
  hipLaunchKernelGGL(fuse12_softmax, dim3(1024), dim3(256), 0, stream, buf1, mask, buf0);
  hipLaunchKernelGGL(build_p, dim3(1024), dim3(256), 0, stream, buf0, Pb);
  hipLaunchKernelGGL(deconv_gemm, dim3(256), dim3(256), 0, stream, Pb, Wt, out);
}

// Round 14
// 110.172 us; speedup vs baseline: 1.2289x; 1.0253x over previous
//
#include <hip/hip_runtime.h>
#include <math.h>

#define NS 4
#define NC 128
#define HH 64
#define WW 64
#define LL 1024   // 32*32

typedef unsigned short u16;
typedef u16 u16x4 __attribute__((ext_vector_type(4)));
typedef short s16x8 __attribute__((ext_vector_type(8)));
typedef float f32x4 __attribute__((ext_vector_type(4)));

__device__ __forceinline__ u16 f2bf(float x) {
  unsigned u = __float_as_uint(x);
  return (u16)((u + 0x7FFFu + ((u >> 16) & 1u)) >> 16);
}
__device__ __forceinline__ float bf2f(u16 h) {
  return __uint_as_float(((unsigned)h) << 16);
}
__device__ __forceinline__ void gload16(const void* g, void* l) {
  __builtin_amdgcn_global_load_lds((const __attribute__((address_space(1))) void*)g,
                                   (__attribute__((address_space(3))) void*)l, 16, 0, 0);
}

// ---------------- K1: prep (256 blocks) + prep_wt (2048 blocks) in one launch
__global__ __launch_bounds__(256) void prep_all(const float* __restrict__ f,
                                                const float* __restrict__ b,
                                                u16* __restrict__ bsT_hi, u16* __restrict__ bsT_lo,
                                                u16* __restrict__ fsT_hi, u16* __restrict__ fsT_lo,
                                                float* __restrict__ Qp,
                                                u16* __restrict__ Wt) {
  int bx = blockIdx.x;
  int t = threadIdx.x;
  __shared__ float Lb[32][68];
  __shared__ float Lf[32][68];
  __shared__ float SS[256];
  if (bx < 256) {
    int cg = bx & 1, qh = (bx >> 1) & 31, s = bx >> 6;
    const float* brow = b + ((size_t)(s * NC + cg * 64) * HH + 2 * qh) * WW;
    const float* frow = f + ((size_t)(s * NC + cg * 64) * HH + 2 * qh) * WW;
#pragma unroll
    for (int i = 0; i < 4; ++i) {
      int task = i * 256 + t;
      int c = task >> 4, j = task & 15;
      float4 vb = *(const float4*)(brow + (size_t)c * (HH * WW) + 4 * j);
      float4 vf = *(const float4*)(frow + (size_t)c * (HH * WW) + 4 * j);
      Lb[2 * j][c] = vb.x; Lb[2 * j + 1][c] = vb.z;
      Lf[2 * j][c] = vf.x; Lf[2 * j + 1][c] = vf.z;
    }
    __syncthreads();
    int qw = t >> 3, og = t & 7;
    int col = og * 8;
    int q = qh * 32 + qw;
    float ssq = 0.f;
    s16x8 vbh, vbl, vfh, vfl;
#pragma unroll
    for (int e = 0; e < 8; ++e) {
      float xb = Lb[qw][col + e], xf = Lf[qw][col + e];
      ssq += xb * xb;
      u16 hb = f2bf(xb); u16 lb = f2bf(xb - bf2f(hb));
      u16 hf = f2bf(xf); u16 lf = f2bf(xf - bf2f(hf));
      vbh[e] = (short)hb; vbl[e] = (short)lb; vfh[e] = (short)hf; vfl[e] = (short)lf;
    }
    size_t o = ((size_t)(s * LL) + q) * NC + cg * 64 + col;
    *(s16x8*)(bsT_hi + o) = vbh;
    *(s16x8*)(bsT_lo + o) = vbl;
    *(s16x8*)(fsT_hi + o) = vfh;
    *(s16x8*)(fsT_lo + o) = vfl;
    SS[t] = ssq;
    __syncthreads();
    if (og == 0) {
      float sum = 0.f;
#pragma unroll
      for (int j = 0; j < 8; ++j) sum += SS[qw * 8 + j];
      Qp[cg * (NS * LL) + s * LL + q] = sum;
    }
  } else {
    int b2 = bx - 256;
    int khg = b2 & 3, c = (b2 >> 2) & 127, s = b2 >> 9;
    float (*Lw)[68] = Lb;
    const float* src = b + ((size_t)(s * NC + c) * HH + 16 * khg) * WW;
    float4 v = *(const float4*)(src + (t >> 4) * WW + (t & 15) * 4);
    int rr = t >> 4, qq4 = (t & 15) * 4;
    Lw[rr][qq4] = v.x; Lw[rr][qq4 + 1] = v.y; Lw[rr][qq4 + 2] = v.z; Lw[rr][qq4 + 3] = v.w;
    __syncthreads();
    if (t < 128) {
      int cls = t >> 5, kh_l = (t >> 2) & 7, ko = t & 3;
      int py = cls >> 1, px = cls & 1;
      int y = 2 * kh_l + py;
      s16x8 w;
#pragma unroll
      for (int e = 0; e < 8; ++e) w[e] = (short)f2bf(Lw[y][16 * ko + 2 * e + px]);
      int kh = khg * 8 + kh_l;
      int z = s * 4 + cls;
      *(s16x8*)(Wt + (((size_t)(z * NC + c)) << 10) + kh * 32 + 8 * ko) = w;
    }
  }
}

// ---------------- K2: gram v2 — Gt[q][p] = sum_c fs[c][q]*bs[c][p].
__global__ __launch_bounds__(256) void gram_mfma(const u16* __restrict__ aT_hi,
                                                 const u16* __restrict__ aT_lo,
                                                 const u16* __restrict__ bT_hi,
                                                 const u16* __restrict__ bT_lo,
                                                 float* __restrict__ G) {
  int wid = blockIdx.x * 4 + (threadIdx.x >> 6);  // 2048 = 4s * 32mt2 * 16ngg
  int ngg = wid & 15, mt2 = (wid >> 4) & 31, s = wid >> 9;
  int l = threadIdx.x & 63, lr = l & 15, lg = l >> 4;
  size_t abase = ((size_t)(s * LL) + mt2 * 32 + lr) * NC + lg * 8;
  size_t bbase = ((size_t)(s * LL) + ngg * 64 + lr) * NC + lg * 8;
  f32x4 acc[2][4] = {};
#pragma unroll
  for (int kc = 0; kc < 4; ++kc) {
    int o = kc * 32;
    s16x8 ah0 = *(const s16x8*)(aT_hi + abase + o);
    s16x8 al0 = *(const s16x8*)(aT_lo + abase + o);
    s16x8 ah1 = *(const s16x8*)(aT_hi + abase + (size_t)16 * NC + o);
    s16x8 al1 = *(const s16x8*)(aT_lo + abase + (size_t)16 * NC + o);
#pragma unroll
    for (int nt = 0; nt < 4; ++nt) {
      s16x8 bh = *(const s16x8*)(bT_hi + bbase + (size_t)(nt * 16) * NC + o);
      s16x8 bl = *(const s16x8*)(bT_lo + bbase + (size_t)(nt * 16) * NC + o);
      acc[0][nt] = __builtin_amdgcn_mfma_f32_16x16x32_bf16(ah0, bh, acc[0][nt], 0, 0, 0);
      acc[0][nt] = __builtin_amdgcn_mfma_f32_16x16x32_bf16(ah0, bl, acc[0][nt], 0, 0, 0);
      acc[0][nt] = __builtin_amdgcn_mfma_f32_16x16x32_bf16(al0, bh, acc[0][nt], 0, 0, 0);
      acc[1][nt] = __builtin_amdgcn_mfma_f32_16x16x32_bf16(ah1, bh, acc[1][nt], 0, 0, 0);
      acc[1][nt] = __builtin_amdgcn_mfma_f32_16x16x32_bf16(ah1, bl, acc[1][nt], 0, 0, 0);
      acc[1][nt] = __builtin_amdgcn_mfma_f32_16x16x32_bf16(al1, bh, acc[1][nt], 0, 0, 0);
    }
  }
  float* Gs = G + ((size_t)s << 20);
#pragma unroll
  for (int mtl = 0; mtl < 2; ++mtl) {
    int qrow = mt2 * 32 + mtl * 16 + lg * 4;
#pragma unroll
    for (int nt = 0; nt < 4; ++nt) {
      int p0 = ngg * 64 + nt * 16 + lr;
#pragma unroll
      for (int r = 0; r < 4; ++r)
        Gs[(size_t)(qrow + r) * LL + p0] = acc[mtl][nt][r];
    }
  }
}

// ---------------- K3: sbuildT + nrm folded; async-staged rows
__global__ __launch_bounds__(256) void sbuildT(const float* __restrict__ Gt,
                                               const float* __restrict__ Qp,
                                               float* __restrict__ St) {
  int g = blockIdx.x;              // 1024 = 4s * 32qh * 8qg
  int qg = g & 7, qh = (g >> 3) & 31, s = g >> 8;
  int qw0 = qg * 4;
  int t = threadIdx.x;
  __shared__ float L[18][1024];    // 72 KB
  __shared__ float Qrow[1024];
  const float* Gs = Gt + ((size_t)s << 20);
  {
    int p4 = t * 4;
    float4 a = *(const float4*)(Qp + s * LL + p4);
    float4 c = *(const float4*)(Qp + NS * LL + s * LL + p4);
    float4 r = make_float4(a.x + c.x, a.y + c.y, a.z + c.z, a.w + c.w);
    *(float4*)&Qrow[p4] = r;
  }
#pragma unroll
  for (int slot = 0; slot < 18; ++slot) {
    int dh = slot / 6 - 1, j = slot % 6;
    int qh2 = qh + dh, qw2 = qw0 - 1 + j;
    bool ok = ((unsigned)qh2 < 32u) && ((unsigned)qw2 < 32u);   // block-uniform
    if (ok)
      gload16(Gs + ((size_t)(qh2 * 32 + qw2) << 10) + t * 4, &L[slot][t * 4]);
    else
      *(float4*)&L[slot][t * 4] = make_float4(0.f, 0.f, 0.f, 0.f);
  }
  __syncthreads();
#pragma unroll
  for (int ii = 0; ii < 4; ++ii) {
    int p = ii * 256 + t;
    int ph = p >> 5, pw = p & 31;
    float sum2 = 1152 * 1e-4f;
#pragma unroll
    for (int dh = -1; dh <= 1; ++dh)
#pragma unroll
      for (int dw = -1; dw <= 1; ++dw) {
        int h = ph + dh, w = pw + dw;
        if ((unsigned)h < 32u && (unsigned)w < 32u) sum2 += Qrow[h * 32 + w];
      }
    float nrp = sqrtf(sum2);
#pragma unroll
    for (int qq = 0; qq < 4; ++qq) {
      float acc = 0.f;
#pragma unroll
      for (int dh = -1; dh <= 1; ++dh)
#pragma unroll
        for (int dw = -1; dw <= 1; ++dw) {
          int ph2 = ph + dh, pw2 = pw + dw;
          if ((unsigned)ph2 < 32u && (unsigned)pw2 < 32u)
            acc += L[(dh + 1) * 6 + qq + dw + 1][p + dh * 32 + dw];
        }
      St[((size_t)s << 20) + ((size_t)(qh * 32 + qw0 + qq) << 10) + p] = acc / nrp;
    }
  }
}

// ---------------- K4: fuse12 + softmax + mask-mean folded; async-staged rows
__global__ __launch_bounds__(256) void fuse12_softmax(const float* __restrict__ St,
                                                      const float* __restrict__ mask,
                                                      float* __restrict__ yiT) {
  int g = blockIdx.x;              // 1024 = 4s * 32qh * 8qg
  int qg = g & 7, qh = (g >> 3) & 31, s = g >> 8;
  int qw0 = qg * 4;
  int q0 = qh * 32 + qw0;
  int t = threadIdx.x;
  int lane = t & 63, wv = t >> 6;
  __shared__ float L[18][1024];    // 72 KB
  __shared__ float Mrow[1024];
  __shared__ float redA[4][4];
  __shared__ float redB[4][4];
  const float* Ss = St + ((size_t)s << 20);
  {
    int p4 = t * 4;
    const float* mrow = mask + s * HH * WW + ((p4 >> 5) * 2) * WW + (p4 & 31) * 2;
    float4 a = *(const float4*)mrow;
    float4 c = *(const float4*)(mrow + 4);
    *(float4*)&Mrow[p4] = make_float4(a.x, a.z, c.x, c.z);
  }
  int base[3];
  base[0] = (qh > 0) ? (q0 - 33) : (992 + qw0 - 2);
  base[1] = q0 - 1;
  base[2] = (qh < 31) ? (q0 + 31) : qw0;
#pragma unroll
  for (int slot = 0; slot < 18; ++slot) {
    int d2 = slot / 6, j = slot % 6;
    int row = base[d2] + j;
    bool ok = (unsigned)row < 1024u;                            // block-uniform
    if (ok)
      gload16(Ss + ((size_t)row << 10) + t * 4, &L[slot][t * 4]);
    else
      *(float4*)&L[slot][t * 4] = make_float4(0.f, 0.f, 0.f, 0.f);
  }
  __syncthreads();
  bool vq0[4], vq2[4];
#pragma unroll
  for (int qq = 0; qq < 4; ++qq) {
    int qw = qw0 + qq;
    vq0[qq] = !(qh == 0 && qw == 0);
    vq2[qq] = !(qh == 31 && qw == 31);
  }
  float v[4][4];
  float mval[4];
  float mxq[4] = {-1e30f, -1e30f, -1e30f, -1e30f};
#pragma unroll
  for (int ii = 0; ii < 4; ++ii) {
    int p = ii * 256 + t;
    int ph = p >> 5, pw = p & 31;
    float msum = 0.f;
#pragma unroll
    for (int dh = -1; dh <= 1; ++dh)
#pragma unroll
      for (int dw = -1; dw <= 1; ++dw) {
        int h = ph + dh, w = pw + dw;
        if ((unsigned)h < 32u && (unsigned)w < 32u) msum += Mrow[h * 32 + w];
      }
    mval[ii] = msum * (1.f / 9.f);
    int rp[3]; bool vp[3];
    if (ph > 0)      { rp[0] = p - 32;        vp[0] = true; }
    else if (pw > 0) { rp[0] = 992 + pw - 1;  vp[0] = true; }
    else             { rp[0] = 0;             vp[0] = false; }
    rp[1] = p; vp[1] = true;
    if (ph < 31)      { rp[2] = p + 32;   vp[2] = true; }
    else if (pw < 31) { rp[2] = pw + 1;   vp[2] = true; }
    else              { rp[2] = 0;        vp[2] = false; }
#pragma unroll
    for (int qq = 0; qq < 4; ++qq) {
      float acc = 0.f;
#pragma unroll
      for (int d2 = 0; d2 < 3; ++d2) {
        bool vq = (d2 == 0) ? vq0[qq] : ((d2 == 2) ? vq2[qq] : true);
        if (vq && vp[d2]) {
#pragma unroll
          for (int d1 = -1; d1 <= 1; ++d1) {
            int cc = rp[d2] + d1;
            if ((unsigned)cc < 1024u)
              acc += L[d2 * 6 + qq + d1 + 1][cc];
          }
        }
      }
      float val = acc * mval[ii] * 10.f;
      v[ii][qq] = val;
      mxq[qq] = fmaxf(mxq[qq], val);
    }
  }
#pragma unroll
  for (int qq = 0; qq < 4; ++qq) {
    float m = mxq[qq];
#pragma unroll
    for (int o = 32; o; o >>= 1) m = fmaxf(m, __shfl_xor(m, o));
    if (lane == 0) redA[wv][qq] = m;
  }
  __syncthreads();
  float fm[4], sq[4] = {0.f, 0.f, 0.f, 0.f};
#pragma unroll
  for (int qq = 0; qq < 4; ++qq)
    fm[qq] = fmaxf(fmaxf(redA[0][qq], redA[1][qq]), fmaxf(redA[2][qq], redA[3][qq]));
#pragma unroll
  for (int ii = 0; ii < 4; ++ii)
#pragma unroll
    for (int qq = 0; qq < 4; ++qq) {
      v[ii][qq] = __expf(v[ii][qq] - fm[qq]);
      sq[qq] += v[ii][qq];
    }
#pragma unroll
  for (int qq = 0; qq < 4; ++qq) {
    float sm = sq[qq];
#pragma unroll
    for (int o = 32; o; o >>= 1) sm += __shfl_xor(sm, o);
    if (lane == 0) redB[wv][qq] = sm;
  }
  __syncthreads();
  float inv[4];
#pragma unroll
  for (int qq = 0; qq < 4; ++qq)
    inv[qq] = 1.f / ((redB[0][qq] + redB[1][qq]) + (redB[2][qq] + redB[3][qq]));
#pragma unroll
  for (int qq = 0; qq < 4; ++qq) {
    float* yo = yiT + ((size_t)s << 20) + ((size_t)(q0 + qq) << 10);
#pragma unroll
    for (int ii = 0; ii < 4; ++ii) {
      int p = ii * 256 + t;
      yo[p] = v[ii][qq] * inv[qq] * mval[ii];
    }
  }
}

// ---------------- K5: build P (4-tap diagonal sums of yiT) as bf16; async-staged
__global__ __launch_bounds__(256) void build_p(const float* __restrict__ yiT,
                                               u16* __restrict__ Pb) {
  int bx = blockIdx.x;               // 1024 = 4s * 32ih * 8jg
  int jg = bx & 7, ih = (bx >> 3) & 31, s = bx >> 8;
  int jw0 = jg * 4;
  const float* Y = yiT + ((size_t)s << 20);
  __shared__ float R[18][1024];
  int t = threadIdx.x;
#pragma unroll
  for (int r = 0; r < 18; ++r) {
    int di = r / 6, jj = r % 6;
    int ihh = ih + di - 1, jww = jw0 + jj - 1;
    bool vld = ((unsigned)ihh < 32u) && ((unsigned)jww < 32u);  // block-uniform
    if (vld)
      gload16(Y + ((size_t)(ihh * 32 + jww) << 10) + t * 4, &R[r][t * 4]);
    else
      *(float4*)&R[r][t * 4] = make_float4(0.f, 0.f, 0.f, 0.f);
  }
  __syncthreads();
  int nl = t >> 6, lane = t & 63;
  int n = ih * 32 + jw0 + nl;
#pragma unroll
  for (int kq = 0; kq < 4; ++kq) {
    int k0 = (kq * 64 + lane) * 4;
    int kh = k0 >> 5;
#pragma unroll
    for (int cls = 0; cls < 4; ++cls) {
      int py = cls >> 1, px = cls & 1;
      int sy = py ? 1 : -1, sx = px ? 1 : -1;
      const float* RA = R[6 + nl + 1];
      const float* RB = R[(1 + sy) * 6 + nl + 1];
      const float* RC = R[6 + nl + 1 + sx];
      const float* RD = R[(1 + sy) * 6 + nl + 1 + sx];
      bool mB = (unsigned)(kh + sy) < 32u;
      int ob = 32 * sy;
      u16x4 pk;
#pragma unroll
      for (int e = 0; e < 4; ++e) {
        int k = k0 + e, kw = k & 31;
        bool mC = (unsigned)(kw + sx) < 32u;
        float v = RA[k];
        if (mB) v += RB[k + ob];
        if (mC) v += RC[k + sx];
        if (mB && mC) v += RD[k + ob + sx];
        pk[e] = f2bf(v);
      }
      int zz = s * 4 + cls;
      *(u16x4*)(Pb + (((size_t)(zz * LL + n)) << 10) + k0) = pk;
    }
  }
}

// ---------------- K6: deconv GEMM v6 — 64c x 64n blocks (512 = 2/CU) so barrier
// drains overlap across co-resident blocks; gload_lds double-buffer, BK=64.
__global__ __launch_bounds__(256) void deconv_gemm(const u16* __restrict__ Pb,
                                                   const u16* __restrict__ Wt,
                                                   float* __restrict__ out) {
  int bx = blockIdx.x;               // 512 = 16z * 2cb * 16nb
  int nb = bx & 15, cb = (bx >> 4) & 1, z = bx >> 5;
  int s = z >> 2, cls = z & 3, py = cls >> 1, px = cls & 1;
  int t = threadIdx.x, w = t >> 6, l = t & 63, lr = l & 15, lg = l >> 4;
  int wc = w >> 1, wn = w & 1;
  int c0 = cb * 64, n0 = nb * 64;
  __shared__ __align__(16) u16 SA[2][64 * 64];    // 8 KB per buf
  __shared__ __align__(16) u16 SB[2][64 * 64];    // 8 KB per buf
  const u16* Ag = Wt + ((size_t)(z * NC + c0)) * LL;
  const u16* Bg = Pb + ((size_t)(z * LL + n0)) * LL;
  int rA  = l >> 3;                       // row within 8-row chunk
  int swz = ((l & 7) ^ (rA & 7)) * 8;     // pre-swizzled source octet (elems)

  auto STAGE = [&](int buf, int k0) {
#pragma unroll
    for (int j = 0; j < 4; ++j) {
      int ci = w * 4 + j;                 // 0..15
      if (ci < 8) {
        const u16* src = Ag + ((size_t)(ci * 8 + rA)) * LL + k0 + swz;
        gload16(src, &SA[buf][ci * 512]);
      } else {
        int cj = ci - 8;
        const u16* src = Bg + ((size_t)(cj * 8 + rA)) * LL + k0 + swz;
        gload16(src, &SB[buf][cj * 512]);
      }
    }
  };
#define ARD(r, o) (*(const s16x8*)((const char*)&SA[buf][0] + (r) * 128 + (((o) * 16) ^ (((r) & 7) << 4))))
#define BRD(r, o) (*(const s16x8*)((const char*)&SB[buf][0] + (r) * 128 + (((o) * 16) ^ (((r) & 7) << 4))))

  f32x4 acc[2][2] = {};
  int buf = 0;
  STAGE(0, 0);
#pragma unroll 1
  for (int it = 0; it < 16; ++it) {
    __syncthreads();                      // staged tile visible
    if (it < 15) STAGE(buf ^ 1, (it + 1) * 64);
#pragma unroll
    for (int ks = 0; ks < 2; ++ks) {
      int o = ks * 4 + lg;
      s16x8 a0 = ARD(wc * 32 + lr, o);
      s16x8 a1 = ARD(wc * 32 + 16 + lr, o);
      s16x8 b0 = BRD(wn * 32 + lr, o);
      s16x8 b1 = BRD(wn * 32 + 16 + lr, o);
      acc[0][0] = __builtin_amdgcn_mfma_f32_16x16x32_bf16(a0, b0, acc[0][0], 0, 0, 0);
      acc[0][1] = __builtin_amdgcn_mfma_f32_16x16x32_bf16(a0, b1, acc[0][1], 0, 0, 0);
      acc[1][0] = __builtin_amdgcn_mfma_f32_16x16x32_bf16(a1, b0, acc[1][0], 0, 0, 0);
      acc[1][1] = __builtin_amdgcn_mfma_f32_16x16x32_bf16(a1, b1, acc[1][1], 0, 0, 0);
    }
    __syncthreads();                      // reads done before buf reuse
    buf ^= 1;
  }
  float* os = out + (size_t)s * NC * HH * WW;
#pragma unroll
  for (int mt = 0; mt < 2; ++mt) {
    int cc = c0 + wc * 32 + mt * 16 + lg * 4;
#pragma unroll
    for (int nt = 0; nt < 2; ++nt) {
      int nn = n0 + wn * 32 + nt * 16 + lr;
      size_t ob = (size_t)(2 * (nn >> 5) + py) * WW + 2 * (nn & 31) + px;
#pragma unroll
      for (int r = 0; r < 4; ++r)
        os[(size_t)(cc + r) * (HH * WW) + ob] = acc[mt][nt][r] * 0.25f;
    }
  }
#undef ARD
#undef BRD
}

extern "C" void kernel_launch(void* const* d_in, const int* in_sizes, int n_in,
                              void* d_out, int out_size, void* d_ws, size_t ws_size,
                              hipStream_t stream) {
  const float* f    = (const float*)d_in[0];
  const float* b    = (const float*)d_in[1];
  const float* mask = (const float*)d_in[2];
  float* out  = (float*)d_out;

  float* buf0 = (float*)d_ws;              // Gt -> yiT
  float* buf1 = buf0 + 4194304;            // St
  u16* bsT_hi = (u16*)(buf1 + 4194304);
  u16* bsT_lo = bsT_hi + 524288;
  u16* fsT_hi = bsT_lo + 524288;
  u16* fsT_lo = fsT_hi + 524288;
  u16* Wt     = fsT_lo + 524288;           // 2,097,152 u16
  float* Qp   = (float*)(Wt + 2097152);    // 8,192
  u16* Pb     = (u16*)(Qp + 8192);         // 16,777,216 u16 (32 MB)

  hipLaunchKernelGGL(prep_all, dim3(2304), dim3(256), 0, stream, f, b, bsT_hi, bsT_lo, fsT_hi, fsT_lo, Qp, Wt);
  hipLaunchKernelGGL(gram_mfma, dim3(512), dim3(256), 0, stream, fsT_hi, fsT_lo, bsT_hi, bsT_lo, buf0);
  hipLaunchKernelGGL(sbuildT, dim3(1024), dim3(256), 0, stream, buf0, Qp, buf1);
  hipLaunchKernelGGL(fuse12_softmax, dim3(1024), dim3(256), 0, stream, buf1, mask, buf0);
  hipLaunchKernelGGL(build_p, dim3(1024), dim3(256), 0, stream, buf0, Pb);
  hipLaunchKernelGGL(deconv_gemm, dim3(512), dim3(256), 0, stream, Pb, Wt, out);
}